// Round 13
// baseline (1287.667 us; speedup 1.0000x reference)
//
#include <hip/hip_runtime.h>

#define D 48
#define C 16
#define H 128
#define D3 (D*D*D)
#define NVOX (2*D3)           // 221184
#define NB_FC (NVOX/128)      // 1728 blocks for k_fc0
#define BN_EPS 1e-5f

// padded channel-major volume: [b][c][54 z][54 y][56 x]
#define PROW 56
#define PPL  (54*PROW)        // 3024
#define PVOL (54*PPL)         // 163296
#define NPAD (54*54*54)       // 157464

typedef unsigned short u16;
typedef unsigned int   u32;

__device__ __forceinline__ float bf2f(u16 u) {
    union { u32 i; float f; } p; p.i = ((u32)u) << 16; return p.f;
}
__device__ __forceinline__ u16 f2bf(float f) {
    union { float f; u32 i; } p; p.f = f;
    u32 r = p.i + 0x7fffu + ((p.i >> 16) & 1u);   // RTNE
    return (u16)(r >> 16);
}
__device__ __forceinline__ int refl(int i) {
    return i < 0 ? -i : (i >= D ? 2*D - 2 - i : i);
}
__device__ __forceinline__ void fma4(float4& a, float s, const float4 w) {
    a.x = fmaf(s, w.x, a.x); a.y = fmaf(s, w.y, a.y);
    a.z = fmaf(s, w.z, a.z); a.w = fmaf(s, w.w, a.w);
}

// ---------------------------------------------------------------------------
// k_pad0: build full padded volume from channels-last x_in (once, step 0).
// ---------------------------------------------------------------------------
__global__ __launch_bounds__(256)
void k_pad0(const float* __restrict__ x, float* __restrict__ xp) {
    const int idx = blockIdx.x * 256 + threadIdx.x;     // 32*NPAD exactly
    const int bc = idx / NPAD;
    int r = idx - bc * NPAD;
    const int pz = r / 2916; r -= pz * 2916;
    const int py = r / 54;
    const int px = r - py * 54;
    const int b = bc >> 4, c = bc & 15;
    const int z = refl(pz - 3), y = refl(py - 3), x0 = refl(px - 3);
    xp[(size_t)bc*PVOL + pz*PPL + py*PROW + px] =
        x[(((size_t)(b*D + z))*D + y)*D*C + x0*C + c];
}

// ---------------------------------------------------------------------------
// k_halo: refresh halo shells from interior (interior written by k_apply).
// ---------------------------------------------------------------------------
__global__ __launch_bounds__(256)
void k_halo(float* __restrict__ xp) {
    const int idx = blockIdx.x * 256 + threadIdx.x;
    const int bc = idx / NPAD;
    int r = idx - bc * NPAD;
    const int pz = r / 2916; r -= pz * 2916;
    const int py = r / 54;
    const int px = r - py * 54;
    if (pz >= 3 && pz < 51 && py >= 3 && py < 51 && px >= 3 && px < 51) return;
    const int sz = refl(pz-3) + 3, sy = refl(py-3) + 3, sx = refl(px-3) + 3;
    xp[(size_t)bc*PVOL + pz*PPL + py*PROW + px] =
        xp[(size_t)bc*PVOL + sz*PPL + sy*PROW + sx];
}

// ---------------------------------------------------------------------------
// k_wxpose: conv weights [kidx][c] -> wt[c][dy][dz][dx]. Run once.
// ---------------------------------------------------------------------------
__global__ __launch_bounds__(256)
void k_wxpose(const float* __restrict__ cw, float* __restrict__ wt) {
    int i = blockIdx.x * 256 + threadIdx.x;
    if (i < 343 * 16) {
        int kidx = i >> 4, c = i & 15;           // kidx = (dz*7+dy)*7+dx
        int dz = kidx / 49, dy = (kidx / 7) % 7, dx = kidx % 7;
        wt[((c*7 + dy)*7 + dz)*7 + dx] = cw[i];
    }
}

// ---------------------------------------------------------------------------
// k_conv v6 (unchanged): no LDS/barriers; weights register-cached per dy.
// ---------------------------------------------------------------------------
__global__ __launch_bounds__(192)
void k_conv(const float* __restrict__ xp, const float* __restrict__ wt,
            const float* __restrict__ cbias, u16* __restrict__ y1m) {
    const int bid = blockIdx.x;
    const int zt = bid & 15;          // 16 z-tiles of 3
    const int yt = (bid >> 4) % 3;    // 3 y-tiles of 16
    const int c  = (bid / 48) & 15;
    const int b  = bid / 768;
    const int t  = threadIdx.x;
    const int tx = t % 12, ty = t / 12;
    const int y0 = yt * 16, z0 = zt * 3;
    const float* base = xp + (size_t)(b*16 + c) * PVOL
                           + (size_t)(y0 + ty) * PROW + 4*tx
                           + (size_t)z0 * PPL;
    const float* wc = wt + c * 343;   // [dy][dz][dx]

    float a[3][4];
    #pragma unroll
    for (int k = 0; k < 3; ++k)
        a[k][0] = a[k][1] = a[k][2] = a[k][3] = 0.f;

    for (int dy = 0; dy < 7; ++dy) {              // runtime: body fits I$
        float w[49];
        const float* wrow = wc + dy*49;
        #pragma unroll
        for (int q = 0; q < 12; ++q) {
            float4 p = *(const float4*)(wrow + q*4);
            w[q*4+0] = p.x; w[q*4+1] = p.y; w[q*4+2] = p.z; w[q*4+3] = p.w;
        }
        w[48] = wrow[48];
        const float* rowb = base + (size_t)dy * PROW;
        #pragma unroll
        for (int pz = 0; pz < 9; ++pz) {          // input plane zi = z0+pz-3
            const float* rp = rowb + (size_t)pz * PPL;
            float4 A  = *(const float4*)rp;
            float4 Bv = *(const float4*)(rp + 4);
            float4 Cv = *(const float4*)(rp + 8);
            #pragma unroll
            for (int k = 0; k < 3; ++k) {
                const int dz = pz - k;            // compile-time
                if (dz >= 0 && dz <= 6) {
                    const float w0=w[dz*7+0], w1=w[dz*7+1], w2=w[dz*7+2],
                                w3=w[dz*7+3], w4=w[dz*7+4], w5=w[dz*7+5],
                                w6=w[dz*7+6];
                    a[k][0] = fmaf(w0,A.x, fmaf(w1,A.y, fmaf(w2,A.z, fmaf(w3,A.w,
                              fmaf(w4,Bv.x, fmaf(w5,Bv.y, fmaf(w6,Bv.z, a[k][0])))))));
                    a[k][1] = fmaf(w0,A.y, fmaf(w1,A.z, fmaf(w2,A.w, fmaf(w3,Bv.x,
                              fmaf(w4,Bv.y, fmaf(w5,Bv.z, fmaf(w6,Bv.w, a[k][1])))))));
                    a[k][2] = fmaf(w0,A.z, fmaf(w1,A.w, fmaf(w2,Bv.x, fmaf(w3,Bv.y,
                              fmaf(w4,Bv.z, fmaf(w5,Bv.w, fmaf(w6,Cv.x, a[k][2])))))));
                    a[k][3] = fmaf(w0,A.w, fmaf(w1,Bv.x, fmaf(w2,Bv.y, fmaf(w3,Bv.z,
                              fmaf(w4,Bv.w, fmaf(w5,Cv.x, fmaf(w6,Cv.y, a[k][3])))))));
                }
            }
        }
    }

    const float cbv = cbias[c];
    const size_t cb_off = (size_t)(b*16 + c) * D3;
    #pragma unroll
    for (int k = 0; k < 3; ++k) {
        const size_t sp = (size_t)(z0+k)*2304 + (y0+ty)*48 + 4*tx;
        ushort4 o = { f2bf(a[k][0]+cbv), f2bf(a[k][1]+cbv),
                      f2bf(a[k][2]+cbv), f2bf(a[k][3]+cbv) };
        *(ushort4*)(y1m + cb_off + sp) = o;
    }
}

// ---------------------------------------------------------------------------
// k_fc0 v13: identical to v12 EXCEPT __launch_bounds__(256, 4): min 4
// waves/SIMD -> 128-VGPR budget. v11 (VGPR=84) and v12 (VGPR=52) proved the
// allocator discards the weight cache to chase wave slots unless given an
// explicit occupancy contract; ~100-110 VGPR needed for wr[32]+x+misc.
// ---------------------------------------------------------------------------
__global__ __launch_bounds__(256, 4)
void k_fc0(const float* __restrict__ srcx, const u16* __restrict__ y1m,
           const float* __restrict__ w0, const float* __restrict__ b0,
           u16* __restrict__ hb, float* __restrict__ partials) {
    __shared__ u16 ys[16][128];       // 4 KB: 16 c x 128 vox
    __shared__ float red[2][4][H];    // 4 KB
    const int t = threadIdx.x;
    const int vb0 = blockIdx.x * 128;
    const int b  = vb0 / D3;
    const int sp0 = vb0 - b * D3;
    {   // stage y1 tile: 512 ushort4, 2 per thread, coalesced per channel
        const u16* yb = y1m + (size_t)b*16*D3 + sp0;
        #pragma unroll
        for (int r = 0; r < 2; ++r) {
            const int idx = t + 256*r;          // 0..511
            const int cc = idx >> 5, q = idx & 31;
            *(ushort4*)&ys[cc][q*4] = *(const ushort4*)(yb + (size_t)cc*D3 + q*4);
        }
    }
    const int j2 = t & 63, vg = t >> 6;         // vg = wave index
    const int j0 = j2 * 2;
    float2 wr[32];                              // 64 VGPR weight cache
    #pragma unroll
    for (int k = 0; k < 32; ++k) wr[k] = *(const float2*)(w0 + k*H + j0);
    const float2 bv = *(const float2*)(b0 + j0);
    __syncthreads();

    float2 sum = {0.f,0.f}, sq = {0.f,0.f};
    const int vloc = vg * 32;
    const float* xc = srcx + (size_t)(vb0 + vloc) * C;
    for (int i = 0; i < 32; ++i) {
        const int vi = vloc + i;
        float h0 = bv.x, h1 = bv.y;
        {   // x part: 4 wave-uniform float4 loads
            const float4* xp4 = (const float4*)(xc + i*C);
            float4 x0 = xp4[0], x1 = xp4[1], x2 = xp4[2], x3 = xp4[3];
            h0 = fmaf(x0.x, wr[0].x,  h0); h1 = fmaf(x0.x, wr[0].y,  h1);
            h0 = fmaf(x0.y, wr[1].x,  h0); h1 = fmaf(x0.y, wr[1].y,  h1);
            h0 = fmaf(x0.z, wr[2].x,  h0); h1 = fmaf(x0.z, wr[2].y,  h1);
            h0 = fmaf(x0.w, wr[3].x,  h0); h1 = fmaf(x0.w, wr[3].y,  h1);
            h0 = fmaf(x1.x, wr[4].x,  h0); h1 = fmaf(x1.x, wr[4].y,  h1);
            h0 = fmaf(x1.y, wr[5].x,  h0); h1 = fmaf(x1.y, wr[5].y,  h1);
            h0 = fmaf(x1.z, wr[6].x,  h0); h1 = fmaf(x1.z, wr[6].y,  h1);
            h0 = fmaf(x1.w, wr[7].x,  h0); h1 = fmaf(x1.w, wr[7].y,  h1);
            h0 = fmaf(x2.x, wr[8].x,  h0); h1 = fmaf(x2.x, wr[8].y,  h1);
            h0 = fmaf(x2.y, wr[9].x,  h0); h1 = fmaf(x2.y, wr[9].y,  h1);
            h0 = fmaf(x2.z, wr[10].x, h0); h1 = fmaf(x2.z, wr[10].y, h1);
            h0 = fmaf(x2.w, wr[11].x, h0); h1 = fmaf(x2.w, wr[11].y, h1);
            h0 = fmaf(x3.x, wr[12].x, h0); h1 = fmaf(x3.x, wr[12].y, h1);
            h0 = fmaf(x3.y, wr[13].x, h0); h1 = fmaf(x3.y, wr[13].y, h1);
            h0 = fmaf(x3.z, wr[14].x, h0); h1 = fmaf(x3.z, wr[14].y, h1);
            h0 = fmaf(x3.w, wr[15].x, h0); h1 = fmaf(x3.w, wr[15].y, h1);
        }
        #pragma unroll
        for (int k = 0; k < 16; ++k) {          // y1 part: LDS broadcasts
            const float yv = bf2f(ys[k][vi]);
            h0 = fmaf(yv, wr[16+k].x, h0); h1 = fmaf(yv, wr[16+k].y, h1);
        }
        sum.x += h0; sum.y += h1;
        sq.x = fmaf(h0,h0,sq.x); sq.y = fmaf(h1,h1,sq.y);
        ushort2 hu = { f2bf(h0), f2bf(h1) };
        *(ushort2*)(hb + (size_t)(vb0 + vi)*H + j0) = hu;   // 256B/wave
    }
    *(float2*)&red[0][vg][j0] = sum;
    *(float2*)&red[1][vg][j0] = sq;
    __syncthreads();
    const int stat = t >> 7, j = t & 127;
    float acc = 0.f;
    #pragma unroll
    for (int g = 0; g < 4; ++g) acc += red[stat][g][j];
    partials[(size_t)t * NB_FC + blockIdx.x] = acc;
}

// ---------------------------------------------------------------------------
__global__ __launch_bounds__(256)
void k_red(const float* __restrict__ partials, float* __restrict__ sums) {
    const int s = blockIdx.x, t = threadIdx.x;
    const float* row = partials + (size_t)s * NB_FC;
    float a = 0.f;
    for (int i = t; i < NB_FC; i += 256) a += row[i];   // 1728 = 6.75*256
    __shared__ float l[256];
    l[t] = a; __syncthreads();
    if (t < 128) l[t] += l[t + 128];
    __syncthreads();
    if (t < 64) {
        float v = l[t] + l[t + 64];
        #pragma unroll
        for (int off = 32; off; off >>= 1) v += __shfl_down(v, off);
        if (t == 0) sums[s] = v;
    }
}

// ---------------------------------------------------------------------------
// k_apply (round-9 structure, unchanged): 16 vox/block; BN+ReLU -> LDS; fc1
// vs LDS-transposed W1; masked residual -> d_out + padded interior.
// ---------------------------------------------------------------------------
__global__ __launch_bounds__(256)
void k_apply(const u16* __restrict__ hb, const float* __restrict__ srcx,
             const float* __restrict__ w1,
             const float* __restrict__ gamma, const float* __restrict__ beta,
             const float* __restrict__ sums, const int* __restrict__ mask,
             float* __restrict__ xo, float* __restrict__ xp) {
    __shared__ float hs[16][132];
    __shared__ float w1t[16][132];   // [c][j]
    __shared__ float xs[16][17];
    const int t = threadIdx.x;
    const size_t vb = (size_t)blockIdx.x * 16;

    for (int idx = t; idx < H*C; idx += 256)
        w1t[idx & 15][idx >> 4] = w1[idx];          // w1[j][c] -> w1t[c][j]

    {   // phase A: BN-affine + ReLU into LDS
        const int j4 = t & 31, vh = t >> 5;
        const int j0 = j4 * 4;
        const float invN = 1.0f / (float)NVOX;
        const float4 sm = *(const float4*)(sums + j0);
        const float4 sQ = *(const float4*)(sums + H + j0);
        const float4 gm = *(const float4*)(gamma + j0);
        const float4 bt = *(const float4*)(beta + j0);
        float4 sc, sh;
        {
            float m0 = sm.x*invN, m1 = sm.y*invN, m2 = sm.z*invN, m3 = sm.w*invN;
            sc.x = gm.x * rsqrtf(fmaf(-m0,m0,sQ.x*invN) + BN_EPS);
            sc.y = gm.y * rsqrtf(fmaf(-m1,m1,sQ.y*invN) + BN_EPS);
            sc.z = gm.z * rsqrtf(fmaf(-m2,m2,sQ.z*invN) + BN_EPS);
            sc.w = gm.w * rsqrtf(fmaf(-m3,m3,sQ.w*invN) + BN_EPS);
            sh.x = bt.x - m0*sc.x; sh.y = bt.y - m1*sc.y;
            sh.z = bt.z - m2*sc.z; sh.w = bt.w - m3*sc.w;
        }
        #pragma unroll
        for (int rep = 0; rep < 2; ++rep) {
            const int vl = rep*8 + vh;
            ushort4 u = *(const ushort4*)(hb + (vb + vl)*H + j0);
            float4 hp;
            hp.x = fmaxf(0.f, fmaf(bf2f(u.x), sc.x, sh.x));
            hp.y = fmaxf(0.f, fmaf(bf2f(u.y), sc.y, sh.y));
            hp.z = fmaxf(0.f, fmaf(bf2f(u.z), sc.z, sh.z));
            hp.w = fmaxf(0.f, fmaf(bf2f(u.w), sc.w, sh.w));
            *(float4*)&hs[vl][j0] = hp;
        }
    }
    __syncthreads();
    {   // phase B: dx = h'@W1, masked residual, ch-0 freeze
        const int c = t & 15, vi = t >> 4;
        const size_t v = vb + vi;
        float4 acc = {0.f,0.f,0.f,0.f};
        #pragma unroll
        for (int j = 0; j < H; j += 4) {
            float4 hv = *(const float4*)&hs[vi][j];
            float4 wv = *(const float4*)&w1t[c][j];
            acc.x = fmaf(hv.x, wv.x, acc.x); acc.y = fmaf(hv.y, wv.y, acc.y);
            acc.z = fmaf(hv.z, wv.z, acc.z); acc.w = fmaf(hv.w, wv.w, acc.w);
        }
        const float dx = (acc.x + acc.y) + (acc.z + acc.w);
        const float m = (float)mask[v];
        const float xold = srcx[v*C + c];
        const float xn = (c == 0) ? xold : fmaf(dx, m, xold);
        xo[v*C + c] = xn;
        xs[c][vi] = xn;
    }
    __syncthreads();
    {   // phase C: write padded-volume interior for next step's conv
        const int c2 = t >> 4, i2 = t & 15;
        const int b = (int)(vb / D3);
        const int sp = (int)(vb % D3);
        const int z = sp / 2304, yy = (sp % 2304) / 48, x0 = sp % 48;
        xp[(size_t)(b*16 + c2)*PVOL + (size_t)(z+3)*PPL
           + (yy+3)*PROW + (x0+3) + i2] = xs[c2][i2];
    }
}

// ---------------------------------------------------------------------------
extern "C" void kernel_launch(void* const* d_in, const int* in_sizes, int n_in,
                              void* d_out, int out_size, void* d_ws, size_t ws_size,
                              hipStream_t stream) {
    const float* x_in = (const float*)d_in[0];
    const float* cw   = (const float*)d_in[1];
    const float* cb   = (const float*)d_in[2];
    const float* w0   = (const float*)d_in[3];
    const float* b0   = (const float*)d_in[4];
    const float* w1   = (const float*)d_in[5];
    const float* gm   = (const float*)d_in[6];
    const float* bt   = (const float*)d_in[7];
    const int*   mk   = (const int*)d_in[8];
    float* out = (float*)d_out;

    char* p = (char*)d_ws;
    float* xp       = (float*)p;   p += (size_t)32 * PVOL * 4;      // 20.9MB
    u16*   y1m      = (u16*)p;     p += (size_t)NVOX * C * 2;       //  7.1MB
    u16*   hb       = (u16*)p;     p += (size_t)NVOX * H * 2;       // 56.6MB
    float* partials = (float*)p;   p += (size_t)256 * NB_FC * 4;    //  1.8MB
    float* sums     = (float*)p;   p += 256 * 4;
    float* wt       = (float*)p;                                    // 343*16

    k_pad0  <<<32*NPAD/256, 256, 0, stream>>>(x_in, xp);
    k_wxpose<<<22,          256, 0, stream>>>(cw, wt);
    for (int s = 0; s < 8; ++s) {
        const float* srcx = (s == 0) ? x_in : out;
        k_conv <<<1536,    192, 0, stream>>>(xp, wt, cb, y1m);
        k_fc0  <<<NB_FC,   256, 0, stream>>>(srcx, y1m, w0, b0, hb, partials);
        k_red  <<<256,     256, 0, stream>>>(partials, sums);
        k_apply<<<NVOX/16, 256, 0, stream>>>(hb, srcx, w1, gm, bt, sums,
                                             mk + (size_t)s * NVOX, out, xp);
        if (s < 7) k_halo<<<32*NPAD/256, 256, 0, stream>>>(xp);
    }
}

// Round 14
// 1000.196 us; speedup vs baseline: 1.2874x; 1.2874x over previous
//
#include <hip/hip_runtime.h>

#define D 48
#define C 16
#define H 128
#define D3 (D*D*D)
#define NVOX (2*D3)           // 221184
#define NB_FC (NVOX/128)      // 1728 blocks for k_fc0
#define BN_EPS 1e-5f

// padded channel-major volume: [b][c][54 z][54 y][56 x]
#define PROW 56
#define PPL  (54*PROW)        // 3024
#define PVOL (54*PPL)         // 163296
#define NPAD (54*54*54)       // 157464

typedef unsigned short u16;
typedef unsigned int   u32;
typedef __attribute__((ext_vector_type(8))) short bf16x8;   // 8 bf16 = 4 VGPR
typedef __attribute__((ext_vector_type(4))) float f32x4;

__device__ __forceinline__ float bf2f(u16 u) {
    union { u32 i; float f; } p; p.i = ((u32)u) << 16; return p.f;
}
__device__ __forceinline__ u16 f2bf(float f) {
    union { float f; u32 i; } p; p.f = f;
    u32 r = p.i + 0x7fffu + ((p.i >> 16) & 1u);   // RTNE
    return (u16)(r >> 16);
}
__device__ __forceinline__ int refl(int i) {
    return i < 0 ? -i : (i >= D ? 2*D - 2 - i : i);
}

// ---------------------------------------------------------------------------
// k_pad0: build full padded volume from channels-last x_in (once, step 0).
// ---------------------------------------------------------------------------
__global__ __launch_bounds__(256)
void k_pad0(const float* __restrict__ x, float* __restrict__ xp) {
    const int idx = blockIdx.x * 256 + threadIdx.x;     // 32*NPAD exactly
    const int bc = idx / NPAD;
    int r = idx - bc * NPAD;
    const int pz = r / 2916; r -= pz * 2916;
    const int py = r / 54;
    const int px = r - py * 54;
    const int b = bc >> 4, c = bc & 15;
    const int z = refl(pz - 3), y = refl(py - 3), x0 = refl(px - 3);
    xp[(size_t)bc*PVOL + pz*PPL + py*PROW + px] =
        x[(((size_t)(b*D + z))*D + y)*D*C + x0*C + c];
}

// ---------------------------------------------------------------------------
// k_halo: refresh halo shells from interior (interior written by k_apply).
// ---------------------------------------------------------------------------
__global__ __launch_bounds__(256)
void k_halo(float* __restrict__ xp) {
    const int idx = blockIdx.x * 256 + threadIdx.x;
    const int bc = idx / NPAD;
    int r = idx - bc * NPAD;
    const int pz = r / 2916; r -= pz * 2916;
    const int py = r / 54;
    const int px = r - py * 54;
    if (pz >= 3 && pz < 51 && py >= 3 && py < 51 && px >= 3 && px < 51) return;
    const int sz = refl(pz-3) + 3, sy = refl(py-3) + 3, sx = refl(px-3) + 3;
    xp[(size_t)bc*PVOL + pz*PPL + py*PROW + px] =
        xp[(size_t)bc*PVOL + sz*PPL + sy*PROW + sx];
}

// ---------------------------------------------------------------------------
// k_wxpose: conv weights [kidx][c] -> wt[c][dy][dz][dx]; ALSO pre-pack W0
// into MFMA B-fragment lane order: w0f[jt*64 + lane] = uint4 of 8 bf16,
// elem i <-> k = (lane>>4)*8 + i, col j = jt*16 + (lane&15). Run once.
// ---------------------------------------------------------------------------
__global__ __launch_bounds__(256)
void k_wxpose(const float* __restrict__ cw, float* __restrict__ wt,
              const float* __restrict__ w0, uint4* __restrict__ w0f) {
    int i = blockIdx.x * 256 + threadIdx.x;
    if (i < 343 * 16) {
        int kidx = i >> 4, c = i & 15;           // kidx = (dz*7+dy)*7+dx
        int dz = kidx / 49, dy = (kidx / 7) % 7, dx = kidx % 7;
        wt[((c*7 + dy)*7 + dz)*7 + dx] = cw[i];
    }
    if (i < 512) {                               // 8 j-tiles x 64 lanes
        const int jt = i >> 6, l = i & 63;
        const int j = jt*16 + (l & 15), k0 = (l >> 4) * 8;
        u32 v[8];
        #pragma unroll
        for (int q = 0; q < 8; ++q) v[q] = f2bf(w0[(size_t)(k0+q)*H + j]);
        uint4 o = { v[0] | (v[1]<<16), v[2] | (v[3]<<16),
                    v[4] | (v[5]<<16), v[6] | (v[7]<<16) };
        w0f[jt*64 + l] = o;
    }
}

// ---------------------------------------------------------------------------
// k_conv v6 (unchanged): no LDS/barriers; weights register-cached per dy.
// ---------------------------------------------------------------------------
__global__ __launch_bounds__(192)
void k_conv(const float* __restrict__ xp, const float* __restrict__ wt,
            const float* __restrict__ cbias, u16* __restrict__ y1m) {
    const int bid = blockIdx.x;
    const int zt = bid & 15;          // 16 z-tiles of 3
    const int yt = (bid >> 4) % 3;    // 3 y-tiles of 16
    const int c  = (bid / 48) & 15;
    const int b  = bid / 768;
    const int t  = threadIdx.x;
    const int tx = t % 12, ty = t / 12;
    const int y0 = yt * 16, z0 = zt * 3;
    const float* base = xp + (size_t)(b*16 + c) * PVOL
                           + (size_t)(y0 + ty) * PROW + 4*tx
                           + (size_t)z0 * PPL;
    const float* wc = wt + c * 343;   // [dy][dz][dx]

    float a[3][4];
    #pragma unroll
    for (int k = 0; k < 3; ++k)
        a[k][0] = a[k][1] = a[k][2] = a[k][3] = 0.f;

    for (int dy = 0; dy < 7; ++dy) {              // runtime: body fits I$
        float w[49];
        const float* wrow = wc + dy*49;
        #pragma unroll
        for (int q = 0; q < 12; ++q) {
            float4 p = *(const float4*)(wrow + q*4);
            w[q*4+0] = p.x; w[q*4+1] = p.y; w[q*4+2] = p.z; w[q*4+3] = p.w;
        }
        w[48] = wrow[48];
        const float* rowb = base + (size_t)dy * PROW;
        #pragma unroll
        for (int pz = 0; pz < 9; ++pz) {          // input plane zi = z0+pz-3
            const float* rp = rowb + (size_t)pz * PPL;
            float4 A  = *(const float4*)rp;
            float4 Bv = *(const float4*)(rp + 4);
            float4 Cv = *(const float4*)(rp + 8);
            #pragma unroll
            for (int k = 0; k < 3; ++k) {
                const int dz = pz - k;            // compile-time
                if (dz >= 0 && dz <= 6) {
                    const float w0=w[dz*7+0], w1=w[dz*7+1], w2=w[dz*7+2],
                                w3=w[dz*7+3], w4=w[dz*7+4], w5=w[dz*7+5],
                                w6=w[dz*7+6];
                    a[k][0] = fmaf(w0,A.x, fmaf(w1,A.y, fmaf(w2,A.z, fmaf(w3,A.w,
                              fmaf(w4,Bv.x, fmaf(w5,Bv.y, fmaf(w6,Bv.z, a[k][0])))))));
                    a[k][1] = fmaf(w0,A.y, fmaf(w1,A.z, fmaf(w2,A.w, fmaf(w3,Bv.x,
                              fmaf(w4,Bv.y, fmaf(w5,Bv.z, fmaf(w6,Bv.w, a[k][1])))))));
                    a[k][2] = fmaf(w0,A.z, fmaf(w1,A.w, fmaf(w2,Bv.x, fmaf(w3,Bv.y,
                              fmaf(w4,Bv.z, fmaf(w5,Bv.w, fmaf(w6,Cv.x, a[k][2])))))));
                    a[k][3] = fmaf(w0,A.w, fmaf(w1,Bv.x, fmaf(w2,Bv.y, fmaf(w3,Bv.z,
                              fmaf(w4,Bv.w, fmaf(w5,Cv.x, fmaf(w6,Cv.y, a[k][3])))))));
                }
            }
        }
    }

    const float cbv = cbias[c];
    const size_t cb_off = (size_t)(b*16 + c) * D3;
    #pragma unroll
    for (int k = 0; k < 3; ++k) {
        const size_t sp = (size_t)(z0+k)*2304 + (y0+ty)*48 + 4*tx;
        ushort4 o = { f2bf(a[k][0]+cbv), f2bf(a[k][1]+cbv),
                      f2bf(a[k][2]+cbv), f2bf(a[k][3]+cbv) };
        *(ushort4*)(y1m + cb_off + sp) = o;
    }
}

// ---------------------------------------------------------------------------
// k_fc0 v14 (MFMA): h = [x|y1]@W0 + b0 via mfma_f32_16x16x32_bf16. One MFMA
// per 16x16 output tile (K=32 in a single instruction). A: lane=(vox=l&15,
// ks=l>>4); ks 0-1 = x from global (cvt bf16), ks 2-3 = y1 from LDS stage.
// B: pre-packed w0f, 8 coalesced dwordx4 = 32 VGPR, reused 16x. Bias in acc.
// D layout col=lane&15,row=(lane>>4)*4+reg [HW-verified] -> hb store + BN
// partials (padded LDS reduce, deterministic). 128 vox/block, grid 1728.
// ---------------------------------------------------------------------------
__global__ __launch_bounds__(256)
void k_fc0(const float* __restrict__ srcx, const u16* __restrict__ y1m,
           const uint4* __restrict__ w0f, const float* __restrict__ b0,
           u16* __restrict__ hb, float* __restrict__ partials) {
    __shared__ u16 ys[16][128];         // 4 KB
    __shared__ float red[2][128][17];   // 17.4 KB (pitch 17 kills conflicts)
    const int t = threadIdx.x;
    const int lane = t & 63, wv = t >> 6;
    const int vb0 = blockIdx.x * 128;
    const int b  = vb0 / D3;
    const int sp0 = vb0 - b * D3;
    {   // stage y1 tile: 16 c x 128 vox, coalesced per channel
        const u16* yb = y1m + (size_t)b*16*D3 + sp0;
        #pragma unroll
        for (int r = 0; r < 2; ++r) {
            const int idx = t + 256*r;          // 0..511
            const int cc = idx >> 5, q = idx & 31;
            *(ushort4*)&ys[cc][q*4] = *(const ushort4*)(yb + (size_t)cc*D3 + q*4);
        }
    }
    uint4 Bf[8];                        // B fragments, 8 j-tiles
    #pragma unroll
    for (int jt = 0; jt < 8; ++jt) Bf[jt] = w0f[jt*64 + lane];
    float bias[8];
    #pragma unroll
    for (int jt = 0; jt < 8; ++jt) bias[jt] = b0[jt*16 + (lane & 15)];
    __syncthreads();

    float sumr[8], sqr[8];
    #pragma unroll
    for (int jt = 0; jt < 8; ++jt) { sumr[jt] = 0.f; sqr[jt] = 0.f; }

    const int vx = lane & 15, ks = lane >> 4;
    #pragma unroll
    for (int tile = 0; tile < 2; ++tile) {
        const int vfeed = wv*32 + tile*16 + vx;     // voxel this lane FEEDS
        bf16x8 A;
        if (ks < 2) {   // x slice: coalesced 2x float4, cvt to bf16
            const float4* xp4 = (const float4*)(srcx + (size_t)(vb0+vfeed)*C + ks*8);
            float4 p0 = xp4[0], p1 = xp4[1];
            A[0]=(short)f2bf(p0.x); A[1]=(short)f2bf(p0.y);
            A[2]=(short)f2bf(p0.z); A[3]=(short)f2bf(p0.w);
            A[4]=(short)f2bf(p1.x); A[5]=(short)f2bf(p1.y);
            A[6]=(short)f2bf(p1.z); A[7]=(short)f2bf(p1.w);
        } else {        // y1 slice: 8 LDS broadcast-ish u16 reads
            const int c0 = (ks - 2) * 8;
            #pragma unroll
            for (int i = 0; i < 8; ++i) A[i] = (short)ys[c0+i][vfeed];
        }
        const int vrow0 = wv*32 + tile*16 + (ks << 2);  // D rows this lane OWNS
        #pragma unroll
        for (int jt = 0; jt < 8; ++jt) {
            f32x4 acc = { bias[jt], bias[jt], bias[jt], bias[jt] };
            acc = __builtin_amdgcn_mfma_f32_16x16x32_bf16(
                      A, *(bf16x8*)&Bf[jt], acc, 0, 0, 0);
            const int jj = jt*16 + vx;
            #pragma unroll
            for (int r = 0; r < 4; ++r) {
                const float h = acc[r];
                sumr[jt] += h; sqr[jt] = fmaf(h, h, sqr[jt]);
                hb[(size_t)(vb0 + vrow0 + r)*H + jj] = f2bf(h);
            }
        }
    }
    #pragma unroll
    for (int jt = 0; jt < 8; ++jt) {
        red[0][jt*16 + vx][wv*4 + ks] = sumr[jt];
        red[1][jt*16 + vx][wv*4 + ks] = sqr[jt];
    }
    __syncthreads();
    const int stat = t >> 7, j = t & 127;
    float acc = 0.f;
    #pragma unroll
    for (int g = 0; g < 16; ++g) acc += red[stat][j][g];
    partials[(size_t)t * NB_FC + blockIdx.x] = acc;
}

// ---------------------------------------------------------------------------
__global__ __launch_bounds__(256)
void k_red(const float* __restrict__ partials, float* __restrict__ sums) {
    const int s = blockIdx.x, t = threadIdx.x;
    const float* row = partials + (size_t)s * NB_FC;
    float a = 0.f;
    for (int i = t; i < NB_FC; i += 256) a += row[i];   // 1728 = 6.75*256
    __shared__ float l[256];
    l[t] = a; __syncthreads();
    if (t < 128) l[t] += l[t + 128];
    __syncthreads();
    if (t < 64) {
        float v = l[t] + l[t + 64];
        #pragma unroll
        for (int off = 32; off; off >>= 1) v += __shfl_down(v, off);
        if (t == 0) sums[s] = v;
    }
}

// ---------------------------------------------------------------------------
// k_apply (round-9 structure, unchanged): 16 vox/block; BN+ReLU -> LDS; fc1
// vs LDS-transposed W1; masked residual -> d_out + padded interior.
// ---------------------------------------------------------------------------
__global__ __launch_bounds__(256)
void k_apply(const u16* __restrict__ hb, const float* __restrict__ srcx,
             const float* __restrict__ w1,
             const float* __restrict__ gamma, const float* __restrict__ beta,
             const float* __restrict__ sums, const int* __restrict__ mask,
             float* __restrict__ xo, float* __restrict__ xp) {
    __shared__ float hs[16][132];
    __shared__ float w1t[16][132];   // [c][j]
    __shared__ float xs[16][17];
    const int t = threadIdx.x;
    const size_t vb = (size_t)blockIdx.x * 16;

    for (int idx = t; idx < H*C; idx += 256)
        w1t[idx & 15][idx >> 4] = w1[idx];          // w1[j][c] -> w1t[c][j]

    {   // phase A: BN-affine + ReLU into LDS
        const int j4 = t & 31, vh = t >> 5;
        const int j0 = j4 * 4;
        const float invN = 1.0f / (float)NVOX;
        const float4 sm = *(const float4*)(sums + j0);
        const float4 sQ = *(const float4*)(sums + H + j0);
        const float4 gm = *(const float4*)(gamma + j0);
        const float4 bt = *(const float4*)(beta + j0);
        float4 sc, sh;
        {
            float m0 = sm.x*invN, m1 = sm.y*invN, m2 = sm.z*invN, m3 = sm.w*invN;
            sc.x = gm.x * rsqrtf(fmaf(-m0,m0,sQ.x*invN) + BN_EPS);
            sc.y = gm.y * rsqrtf(fmaf(-m1,m1,sQ.y*invN) + BN_EPS);
            sc.z = gm.z * rsqrtf(fmaf(-m2,m2,sQ.z*invN) + BN_EPS);
            sc.w = gm.w * rsqrtf(fmaf(-m3,m3,sQ.w*invN) + BN_EPS);
            sh.x = bt.x - m0*sc.x; sh.y = bt.y - m1*sc.y;
            sh.z = bt.z - m2*sc.z; sh.w = bt.w - m3*sc.w;
        }
        #pragma unroll
        for (int rep = 0; rep < 2; ++rep) {
            const int vl = rep*8 + vh;
            ushort4 u = *(const ushort4*)(hb + (vb + vl)*H + j0);
            float4 hp;
            hp.x = fmaxf(0.f, fmaf(bf2f(u.x), sc.x, sh.x));
            hp.y = fmaxf(0.f, fmaf(bf2f(u.y), sc.y, sh.y));
            hp.z = fmaxf(0.f, fmaf(bf2f(u.z), sc.z, sh.z));
            hp.w = fmaxf(0.f, fmaf(bf2f(u.w), sc.w, sh.w));
            *(float4*)&hs[vl][j0] = hp;
        }
    }
    __syncthreads();
    {   // phase B: dx = h'@W1, masked residual, ch-0 freeze
        const int c = t & 15, vi = t >> 4;
        const size_t v = vb + vi;
        float4 acc = {0.f,0.f,0.f,0.f};
        #pragma unroll
        for (int j = 0; j < H; j += 4) {
            float4 hv = *(const float4*)&hs[vi][j];
            float4 wv = *(const float4*)&w1t[c][j];
            acc.x = fmaf(hv.x, wv.x, acc.x); acc.y = fmaf(hv.y, wv.y, acc.y);
            acc.z = fmaf(hv.z, wv.z, acc.z); acc.w = fmaf(hv.w, wv.w, acc.w);
        }
        const float dx = (acc.x + acc.y) + (acc.z + acc.w);
        const float m = (float)mask[v];
        const float xold = srcx[v*C + c];
        const float xn = (c == 0) ? xold : fmaf(dx, m, xold);
        xo[v*C + c] = xn;
        xs[c][vi] = xn;
    }
    __syncthreads();
    {   // phase C: write padded-volume interior for next step's conv
        const int c2 = t >> 4, i2 = t & 15;
        const int b = (int)(vb / D3);
        const int sp = (int)(vb % D3);
        const int z = sp / 2304, yy = (sp % 2304) / 48, x0 = sp % 48;
        xp[(size_t)(b*16 + c2)*PVOL + (size_t)(z+3)*PPL
           + (yy+3)*PROW + (x0+3) + i2] = xs[c2][i2];
    }
}

// ---------------------------------------------------------------------------
extern "C" void kernel_launch(void* const* d_in, const int* in_sizes, int n_in,
                              void* d_out, int out_size, void* d_ws, size_t ws_size,
                              hipStream_t stream) {
    const float* x_in = (const float*)d_in[0];
    const float* cw   = (const float*)d_in[1];
    const float* cb   = (const float*)d_in[2];
    const float* w0   = (const float*)d_in[3];
    const float* b0   = (const float*)d_in[4];
    const float* w1   = (const float*)d_in[5];
    const float* gm   = (const float*)d_in[6];
    const float* bt   = (const float*)d_in[7];
    const int*   mk   = (const int*)d_in[8];
    float* out = (float*)d_out;

    char* p = (char*)d_ws;
    float* xp       = (float*)p;   p += (size_t)32 * PVOL * 4;      // 20.9MB
    u16*   y1m      = (u16*)p;     p += (size_t)NVOX * C * 2;       //  7.1MB
    u16*   hb       = (u16*)p;     p += (size_t)NVOX * H * 2;       // 56.6MB
    float* partials = (float*)p;   p += (size_t)256 * NB_FC * 4;    //  1.8MB
    float* sums     = (float*)p;   p += 256 * 4;
    float* wt       = (float*)p;   p += 343 * 16 * 4;               // 21.9KB
    uint4* w0f      = (uint4*)p;   p += 512 * 16;                   //  8KB

    k_pad0  <<<32*NPAD/256, 256, 0, stream>>>(x_in, xp);
    k_wxpose<<<22,          256, 0, stream>>>(cw, wt, w0, w0f);
    for (int s = 0; s < 8; ++s) {
        const float* srcx = (s == 0) ? x_in : out;
        k_conv <<<1536,    192, 0, stream>>>(xp, wt, cb, y1m);
        k_fc0  <<<NB_FC,   256, 0, stream>>>(srcx, y1m, w0f, b0, hb, partials);
        k_red  <<<256,     256, 0, stream>>>(partials, sums);
        k_apply<<<NVOX/16, 256, 0, stream>>>(hb, srcx, w1, gm, bt, sums,
                                             mk + (size_t)s * NVOX, out, xp);
        if (s < 7) k_halo<<<32*NPAD/256, 256, 0, stream>>>(xp);
    }
}

// Round 15
// 907.634 us; speedup vs baseline: 1.4187x; 1.1020x over previous
//
#include <hip/hip_runtime.h>

#define D 48
#define C 16
#define H 128
#define D3 (D*D*D)
#define NVOX (2*D3)           // 221184
#define NB_FC (NVOX/128)      // 1728 blocks for k_fc0
#define BN_EPS 1e-5f

// padded channel-major volume (bf16): [b][c][54 z][54 y][56 x]
#define PROW 56
#define PPL  (54*PROW)        // 3024
#define PVOL (54*PPL)         // 163296
#define NPAD (54*54*54)       // 157464

typedef unsigned short u16;
typedef unsigned int   u32;
typedef __attribute__((ext_vector_type(8))) short bf16x8;   // 8 bf16 = 4 VGPR
typedef __attribute__((ext_vector_type(4))) float f32x4;

__device__ __forceinline__ float bf2f(u16 u) {
    union { u32 i; float f; } p; p.i = ((u32)u) << 16; return p.f;
}
__device__ __forceinline__ float lof(u32 u) {   // low bf16 of a u32 pair
    union { u32 i; float f; } p; p.i = u << 16; return p.f;
}
__device__ __forceinline__ float hif(u32 u) {   // high bf16 of a u32 pair
    union { u32 i; float f; } p; p.i = u & 0xFFFF0000u; return p.f;
}
__device__ __forceinline__ u16 f2bf(float f) {
    union { float f; u32 i; } p; p.f = f;
    u32 r = p.i + 0x7fffu + ((p.i >> 16) & 1u);   // RTNE
    return (u16)(r >> 16);
}
__device__ __forceinline__ int refl(int i) {
    return i < 0 ? -i : (i >= D ? 2*D - 2 - i : i);
}

// ---------------------------------------------------------------------------
// k_pad0: build full padded bf16 volume from channels-last x_in (once).
// ---------------------------------------------------------------------------
__global__ __launch_bounds__(256)
void k_pad0(const float* __restrict__ x, u16* __restrict__ xp) {
    const int idx = blockIdx.x * 256 + threadIdx.x;     // 32*NPAD exactly
    const int bc = idx / NPAD;
    int r = idx - bc * NPAD;
    const int pz = r / 2916; r -= pz * 2916;
    const int py = r / 54;
    const int px = r - py * 54;
    const int b = bc >> 4, c = bc & 15;
    const int z = refl(pz - 3), y = refl(py - 3), x0 = refl(px - 3);
    xp[(size_t)bc*PVOL + pz*PPL + py*PROW + px] =
        f2bf(x[(((size_t)(b*D + z))*D + y)*D*C + x0*C + c]);
}

// ---------------------------------------------------------------------------
// k_halo: refresh halo shells from interior (interior written by k_apply).
// ---------------------------------------------------------------------------
__global__ __launch_bounds__(256)
void k_halo(u16* __restrict__ xp) {
    const int idx = blockIdx.x * 256 + threadIdx.x;
    const int bc = idx / NPAD;
    int r = idx - bc * NPAD;
    const int pz = r / 2916; r -= pz * 2916;
    const int py = r / 54;
    const int px = r - py * 54;
    if (pz >= 3 && pz < 51 && py >= 3 && py < 51 && px >= 3 && px < 51) return;
    const int sz = refl(pz-3) + 3, sy = refl(py-3) + 3, sx = refl(px-3) + 3;
    xp[(size_t)bc*PVOL + pz*PPL + py*PROW + px] =
        xp[(size_t)bc*PVOL + sz*PPL + sy*PROW + sx];
}

// ---------------------------------------------------------------------------
// k_wxpose: conv weights [kidx][c] -> wt[c][dy][dz][dx]; ALSO pre-pack W0
// into MFMA B-fragment lane order. Run once.
// ---------------------------------------------------------------------------
__global__ __launch_bounds__(256)
void k_wxpose(const float* __restrict__ cw, float* __restrict__ wt,
              const float* __restrict__ w0, uint4* __restrict__ w0f) {
    int i = blockIdx.x * 256 + threadIdx.x;
    if (i < 343 * 16) {
        int kidx = i >> 4, c = i & 15;           // kidx = (dz*7+dy)*7+dx
        int dz = kidx / 49, dy = (kidx / 7) % 7, dx = kidx % 7;
        wt[((c*7 + dy)*7 + dz)*7 + dx] = cw[i];
    }
    if (i < 512) {                               // 8 j-tiles x 64 lanes
        const int jt = i >> 6, l = i & 63;
        const int j = jt*16 + (l & 15), k0 = (l >> 4) * 8;
        u32 v[8];
        #pragma unroll
        for (int q = 0; q < 8; ++q) v[q] = f2bf(w0[(size_t)(k0+q)*H + j]);
        uint4 o = { v[0] | (v[1]<<16), v[2] | (v[3]<<16),
                    v[4] | (v[5]<<16), v[6] | (v[7]<<16) };
        w0f[jt*64 + l] = o;
    }
}

// ---------------------------------------------------------------------------
// k_conv v7: v6 structure, bf16 input volume. Per (dy,pz) row: 20B of loads
// (uint2+uint2+u32 = exactly the 10 needed elems) + 10 shift/AND unpacks.
// dy-resweep window now ~22 KB -> L1-resident; xp (10.4 MB) L2-resident.
// ---------------------------------------------------------------------------
__global__ __launch_bounds__(192)
void k_conv(const u16* __restrict__ xp, const float* __restrict__ wt,
            const float* __restrict__ cbias, u16* __restrict__ y1m) {
    const int bid = blockIdx.x;
    const int zt = bid & 15;          // 16 z-tiles of 3
    const int yt = (bid >> 4) % 3;    // 3 y-tiles of 16
    const int c  = (bid / 48) & 15;
    const int b  = bid / 768;
    const int t  = threadIdx.x;
    const int tx = t % 12, ty = t / 12;
    const int y0 = yt * 16, z0 = zt * 3;
    const u16* base = xp + (size_t)(b*16 + c) * PVOL
                         + (size_t)(y0 + ty) * PROW + 4*tx
                         + (size_t)z0 * PPL;
    const float* wc = wt + c * 343;   // [dy][dz][dx]

    float a[3][4];
    #pragma unroll
    for (int k = 0; k < 3; ++k)
        a[k][0] = a[k][1] = a[k][2] = a[k][3] = 0.f;

    for (int dy = 0; dy < 7; ++dy) {              // runtime: body fits I$
        float w[49];
        const float* wrow = wc + dy*49;
        #pragma unroll
        for (int q = 0; q < 12; ++q) {
            float4 p = *(const float4*)(wrow + q*4);
            w[q*4+0] = p.x; w[q*4+1] = p.y; w[q*4+2] = p.z; w[q*4+3] = p.w;
        }
        w[48] = wrow[48];
        const u16* rowb = base + (size_t)dy * PROW;
        #pragma unroll
        for (int pz = 0; pz < 9; ++pz) {          // input plane zi = z0+pz-3
            const u16* rp = rowb + (size_t)pz * PPL;
            const uint2 p01 = *(const uint2*)rp;        // elems 0..3 (8B algn)
            const uint2 p23 = *(const uint2*)(rp + 4);  // elems 4..7
            const u32  p4  = *(const u32*)(rp + 8);     // elems 8..9
            const float v0 = lof(p01.x), v1 = hif(p01.x);
            const float v2 = lof(p01.y), v3 = hif(p01.y);
            const float v4 = lof(p23.x), v5 = hif(p23.x);
            const float v6 = lof(p23.y), v7 = hif(p23.y);
            const float v8 = lof(p4),    v9 = hif(p4);
            #pragma unroll
            for (int k = 0; k < 3; ++k) {
                const int dz = pz - k;            // compile-time
                if (dz >= 0 && dz <= 6) {
                    const float w0=w[dz*7+0], w1=w[dz*7+1], w2=w[dz*7+2],
                                w3=w[dz*7+3], w4=w[dz*7+4], w5=w[dz*7+5],
                                w6=w[dz*7+6];
                    a[k][0] = fmaf(w0,v0, fmaf(w1,v1, fmaf(w2,v2, fmaf(w3,v3,
                              fmaf(w4,v4, fmaf(w5,v5, fmaf(w6,v6, a[k][0])))))));
                    a[k][1] = fmaf(w0,v1, fmaf(w1,v2, fmaf(w2,v3, fmaf(w3,v4,
                              fmaf(w4,v5, fmaf(w5,v6, fmaf(w6,v7, a[k][1])))))));
                    a[k][2] = fmaf(w0,v2, fmaf(w1,v3, fmaf(w2,v4, fmaf(w3,v5,
                              fmaf(w4,v6, fmaf(w5,v7, fmaf(w6,v8, a[k][2])))))));
                    a[k][3] = fmaf(w0,v3, fmaf(w1,v4, fmaf(w2,v5, fmaf(w3,v6,
                              fmaf(w4,v7, fmaf(w5,v8, fmaf(w6,v9, a[k][3])))))));
                }
            }
        }
    }

    const float cbv = cbias[c];
    const size_t cb_off = (size_t)(b*16 + c) * D3;
    #pragma unroll
    for (int k = 0; k < 3; ++k) {
        const size_t sp = (size_t)(z0+k)*2304 + (y0+ty)*48 + 4*tx;
        ushort4 o = { f2bf(a[k][0]+cbv), f2bf(a[k][1]+cbv),
                      f2bf(a[k][2]+cbv), f2bf(a[k][3]+cbv) };
        *(ushort4*)(y1m + cb_off + sp) = o;
    }
}

// ---------------------------------------------------------------------------
// k_fc0 v14 (MFMA, unchanged): h = [x|y1]@W0 + b0 via mfma_f32_16x16x32_bf16.
// ---------------------------------------------------------------------------
__global__ __launch_bounds__(256)
void k_fc0(const float* __restrict__ srcx, const u16* __restrict__ y1m,
           const uint4* __restrict__ w0f, const float* __restrict__ b0,
           u16* __restrict__ hb, float* __restrict__ partials) {
    __shared__ u16 ys[16][128];         // 4 KB
    __shared__ float red[2][128][17];   // 17.4 KB (pitch 17 kills conflicts)
    const int t = threadIdx.x;
    const int lane = t & 63, wv = t >> 6;
    const int vb0 = blockIdx.x * 128;
    const int b  = vb0 / D3;
    const int sp0 = vb0 - b * D3;
    {   // stage y1 tile: 16 c x 128 vox, coalesced per channel
        const u16* yb = y1m + (size_t)b*16*D3 + sp0;
        #pragma unroll
        for (int r = 0; r < 2; ++r) {
            const int idx = t + 256*r;          // 0..511
            const int cc = idx >> 5, q = idx & 31;
            *(ushort4*)&ys[cc][q*4] = *(const ushort4*)(yb + (size_t)cc*D3 + q*4);
        }
    }
    uint4 Bf[8];                        // B fragments, 8 j-tiles
    #pragma unroll
    for (int jt = 0; jt < 8; ++jt) Bf[jt] = w0f[jt*64 + lane];
    float bias[8];
    #pragma unroll
    for (int jt = 0; jt < 8; ++jt) bias[jt] = b0[jt*16 + (lane & 15)];
    __syncthreads();

    float sumr[8], sqr[8];
    #pragma unroll
    for (int jt = 0; jt < 8; ++jt) { sumr[jt] = 0.f; sqr[jt] = 0.f; }

    const int vx = lane & 15, ks = lane >> 4;
    #pragma unroll
    for (int tile = 0; tile < 2; ++tile) {
        const int vfeed = wv*32 + tile*16 + vx;     // voxel this lane FEEDS
        bf16x8 A;
        if (ks < 2) {   // x slice: coalesced 2x float4, cvt to bf16
            const float4* xp4 = (const float4*)(srcx + (size_t)(vb0+vfeed)*C + ks*8);
            float4 p0 = xp4[0], p1 = xp4[1];
            A[0]=(short)f2bf(p0.x); A[1]=(short)f2bf(p0.y);
            A[2]=(short)f2bf(p0.z); A[3]=(short)f2bf(p0.w);
            A[4]=(short)f2bf(p1.x); A[5]=(short)f2bf(p1.y);
            A[6]=(short)f2bf(p1.z); A[7]=(short)f2bf(p1.w);
        } else {        // y1 slice: 8 LDS broadcast-ish u16 reads
            const int c0 = (ks - 2) * 8;
            #pragma unroll
            for (int i = 0; i < 8; ++i) A[i] = (short)ys[c0+i][vfeed];
        }
        const int vrow0 = wv*32 + tile*16 + (ks << 2);  // D rows this lane OWNS
        #pragma unroll
        for (int jt = 0; jt < 8; ++jt) {
            f32x4 acc = { bias[jt], bias[jt], bias[jt], bias[jt] };
            acc = __builtin_amdgcn_mfma_f32_16x16x32_bf16(
                      A, *(bf16x8*)&Bf[jt], acc, 0, 0, 0);
            const int jj = jt*16 + vx;
            #pragma unroll
            for (int r = 0; r < 4; ++r) {
                const float h = acc[r];
                sumr[jt] += h; sqr[jt] = fmaf(h, h, sqr[jt]);
                hb[(size_t)(vb0 + vrow0 + r)*H + jj] = f2bf(h);
            }
        }
    }
    #pragma unroll
    for (int jt = 0; jt < 8; ++jt) {
        red[0][jt*16 + vx][wv*4 + ks] = sumr[jt];
        red[1][jt*16 + vx][wv*4 + ks] = sqr[jt];
    }
    __syncthreads();
    const int stat = t >> 7, j = t & 127;
    float acc = 0.f;
    #pragma unroll
    for (int g = 0; g < 16; ++g) acc += red[stat][j][g];
    partials[(size_t)t * NB_FC + blockIdx.x] = acc;
}

// ---------------------------------------------------------------------------
__global__ __launch_bounds__(256)
void k_red(const float* __restrict__ partials, float* __restrict__ sums) {
    const int s = blockIdx.x, t = threadIdx.x;
    const float* row = partials + (size_t)s * NB_FC;
    float a = 0.f;
    for (int i = t; i < NB_FC; i += 256) a += row[i];   // 1728 = 6.75*256
    __shared__ float l[256];
    l[t] = a; __syncthreads();
    if (t < 128) l[t] += l[t + 128];
    __syncthreads();
    if (t < 64) {
        float v = l[t] + l[t + 64];
        #pragma unroll
        for (int off = 32; off; off >>= 1) v += __shfl_down(v, off);
        if (t == 0) sums[s] = v;
    }
}

// ---------------------------------------------------------------------------
// k_apply (round-9 structure): 16 vox/block; BN+ReLU -> LDS; fc1 vs LDS-
// transposed W1; masked residual -> d_out + bf16 padded interior.
// ---------------------------------------------------------------------------
__global__ __launch_bounds__(256)
void k_apply(const u16* __restrict__ hb, const float* __restrict__ srcx,
             const float* __restrict__ w1,
             const float* __restrict__ gamma, const float* __restrict__ beta,
             const float* __restrict__ sums, const int* __restrict__ mask,
             float* __restrict__ xo, u16* __restrict__ xp) {
    __shared__ float hs[16][132];
    __shared__ float w1t[16][132];   // [c][j]
    __shared__ float xs[16][17];
    const int t = threadIdx.x;
    const size_t vb = (size_t)blockIdx.x * 16;

    for (int idx = t; idx < H*C; idx += 256)
        w1t[idx & 15][idx >> 4] = w1[idx];          // w1[j][c] -> w1t[c][j]

    {   // phase A: BN-affine + ReLU into LDS
        const int j4 = t & 31, vh = t >> 5;
        const int j0 = j4 * 4;
        const float invN = 1.0f / (float)NVOX;
        const float4 sm = *(const float4*)(sums + j0);
        const float4 sQ = *(const float4*)(sums + H + j0);
        const float4 gm = *(const float4*)(gamma + j0);
        const float4 bt = *(const float4*)(beta + j0);
        float4 sc, sh;
        {
            float m0 = sm.x*invN, m1 = sm.y*invN, m2 = sm.z*invN, m3 = sm.w*invN;
            sc.x = gm.x * rsqrtf(fmaf(-m0,m0,sQ.x*invN) + BN_EPS);
            sc.y = gm.y * rsqrtf(fmaf(-m1,m1,sQ.y*invN) + BN_EPS);
            sc.z = gm.z * rsqrtf(fmaf(-m2,m2,sQ.z*invN) + BN_EPS);
            sc.w = gm.w * rsqrtf(fmaf(-m3,m3,sQ.w*invN) + BN_EPS);
            sh.x = bt.x - m0*sc.x; sh.y = bt.y - m1*sc.y;
            sh.z = bt.z - m2*sc.z; sh.w = bt.w - m3*sc.w;
        }
        #pragma unroll
        for (int rep = 0; rep < 2; ++rep) {
            const int vl = rep*8 + vh;
            ushort4 u = *(const ushort4*)(hb + (vb + vl)*H + j0);
            float4 hp;
            hp.x = fmaxf(0.f, fmaf(bf2f(u.x), sc.x, sh.x));
            hp.y = fmaxf(0.f, fmaf(bf2f(u.y), sc.y, sh.y));
            hp.z = fmaxf(0.f, fmaf(bf2f(u.z), sc.z, sh.z));
            hp.w = fmaxf(0.f, fmaf(bf2f(u.w), sc.w, sh.w));
            *(float4*)&hs[vl][j0] = hp;
        }
    }
    __syncthreads();
    {   // phase B: dx = h'@W1, masked residual, ch-0 freeze
        const int c = t & 15, vi = t >> 4;
        const size_t v = vb + vi;
        float4 acc = {0.f,0.f,0.f,0.f};
        #pragma unroll
        for (int j = 0; j < H; j += 4) {
            float4 hv = *(const float4*)&hs[vi][j];
            float4 wv = *(const float4*)&w1t[c][j];
            acc.x = fmaf(hv.x, wv.x, acc.x); acc.y = fmaf(hv.y, wv.y, acc.y);
            acc.z = fmaf(hv.z, wv.z, acc.z); acc.w = fmaf(hv.w, wv.w, acc.w);
        }
        const float dx = (acc.x + acc.y) + (acc.z + acc.w);
        const float m = (float)mask[v];
        const float xold = srcx[v*C + c];
        const float xn = (c == 0) ? xold : fmaf(dx, m, xold);
        xo[v*C + c] = xn;
        xs[c][vi] = xn;
    }
    __syncthreads();
    {   // phase C: write bf16 padded-volume interior for next step's conv
        const int c2 = t >> 4, i2 = t & 15;
        const int b = (int)(vb / D3);
        const int sp = (int)(vb % D3);
        const int z = sp / 2304, yy = (sp % 2304) / 48, x0 = sp % 48;
        xp[(size_t)(b*16 + c2)*PVOL + (size_t)(z+3)*PPL
           + (yy+3)*PROW + (x0+3) + i2] = f2bf(xs[c2][i2]);
    }
}

// ---------------------------------------------------------------------------
extern "C" void kernel_launch(void* const* d_in, const int* in_sizes, int n_in,
                              void* d_out, int out_size, void* d_ws, size_t ws_size,
                              hipStream_t stream) {
    const float* x_in = (const float*)d_in[0];
    const float* cw   = (const float*)d_in[1];
    const float* cb   = (const float*)d_in[2];
    const float* w0   = (const float*)d_in[3];
    const float* b0   = (const float*)d_in[4];
    const float* w1   = (const float*)d_in[5];
    const float* gm   = (const float*)d_in[6];
    const float* bt   = (const float*)d_in[7];
    const int*   mk   = (const int*)d_in[8];
    float* out = (float*)d_out;

    char* p = (char*)d_ws;
    u16*   xp       = (u16*)p;     p += (size_t)32 * PVOL * 2;      // 10.4MB
    u16*   y1m      = (u16*)p;     p += (size_t)NVOX * C * 2;       //  7.1MB
    u16*   hb       = (u16*)p;     p += (size_t)NVOX * H * 2;       // 56.6MB
    float* partials = (float*)p;   p += (size_t)256 * NB_FC * 4;    //  1.8MB
    float* sums     = (float*)p;   p += 256 * 4;
    float* wt       = (float*)p;   p += 343 * 16 * 4;               // 21.9KB
    uint4* w0f      = (uint4*)p;   p += 512 * 16;                   //  8KB

    k_pad0  <<<32*NPAD/256, 256, 0, stream>>>(x_in, xp);
    k_wxpose<<<22,          256, 0, stream>>>(cw, wt, w0, w0f);
    for (int s = 0; s < 8; ++s) {
        const float* srcx = (s == 0) ? x_in : out;
        k_conv <<<1536,    192, 0, stream>>>(xp, wt, cb, y1m);
        k_fc0  <<<NB_FC,   256, 0, stream>>>(srcx, y1m, w0f, b0, hb, partials);
        k_red  <<<256,     256, 0, stream>>>(partials, sums);
        k_apply<<<NVOX/16, 256, 0, stream>>>(hb, srcx, w1, gm, bt, sums,
                                             mk + (size_t)s * NVOX, out, xp);
        if (s < 7) k_halo<<<32*NPAD/256, 256, 0, stream>>>(xp);
    }
}

// Round 17
// 699.815 us; speedup vs baseline: 1.8400x; 1.2970x over previous
//
#include <hip/hip_runtime.h>

#define D 48
#define C 16
#define H 128
#define D3 (D*D*D)
#define NVOX (2*D3)           // 221184
#define NB_FC (NVOX/128)      // 1728 blocks
#define BN_EPS 1e-5f

// padded channel-major volume (bf16): [b][c][54 z][54 y][56 x]
#define PROW 56
#define PPL  (54*PROW)        // 3024
#define PVOL (54*PPL)         // 163296
#define NPAD (54*54*54)       // 157464

typedef unsigned short u16;
typedef unsigned int   u32;
typedef __attribute__((ext_vector_type(8))) short bf16x8;   // 8 bf16 = 4 VGPR
typedef __attribute__((ext_vector_type(4))) float f32x4;

__device__ __forceinline__ float bf2f(u16 u) {
    union { u32 i; float f; } p; p.i = ((u32)u) << 16; return p.f;
}
__device__ __forceinline__ float lof(u32 u) {
    union { u32 i; float f; } p; p.i = u << 16; return p.f;
}
__device__ __forceinline__ float hif(u32 u) {
    union { u32 i; float f; } p; p.i = u & 0xFFFF0000u; return p.f;
}
__device__ __forceinline__ u16 f2bf(float f) {
    union { float f; u32 i; } p; p.f = f;
    u32 r = p.i + 0x7fffu + ((p.i >> 16) & 1u);   // RTNE
    return (u16)(r >> 16);
}
__device__ __forceinline__ int refl(int i) {
    return i < 0 ? -i : (i >= D ? 2*D - 2 - i : i);
}

// ---------------------------------------------------------------------------
// k_pad0: build full padded bf16 volume from channels-last x_in (once).
// ---------------------------------------------------------------------------
__global__ __launch_bounds__(256)
void k_pad0(const float* __restrict__ x, u16* __restrict__ xp) {
    const int idx = blockIdx.x * 256 + threadIdx.x;     // 32*NPAD exactly
    const int bc = idx / NPAD;
    int r = idx - bc * NPAD;
    const int pz = r / 2916; r -= pz * 2916;
    const int py = r / 54;
    const int px = r - py * 54;
    const int b = bc >> 4, c = bc & 15;
    const int z = refl(pz - 3), y = refl(py - 3), x0 = refl(px - 3);
    xp[(size_t)bc*PVOL + pz*PPL + py*PROW + px] =
        f2bf(x[(((size_t)(b*D + z))*D + y)*D*C + x0*C + c]);
}

// ---------------------------------------------------------------------------
// k_halo: refresh halo shells from interior (interior written by k_apply).
// ---------------------------------------------------------------------------
__global__ __launch_bounds__(256)
void k_halo(u16* __restrict__ xp) {
    const int idx = blockIdx.x * 256 + threadIdx.x;
    const int bc = idx / NPAD;
    int r = idx - bc * NPAD;
    const int pz = r / 2916; r -= pz * 2916;
    const int py = r / 54;
    const int px = r - py * 54;
    if (pz >= 3 && pz < 51 && py >= 3 && py < 51 && px >= 3 && px < 51) return;
    const int sz = refl(pz-3) + 3, sy = refl(py-3) + 3, sx = refl(px-3) + 3;
    xp[(size_t)bc*PVOL + pz*PPL + py*PROW + px] =
        xp[(size_t)bc*PVOL + sz*PPL + sy*PROW + sx];
}

// ---------------------------------------------------------------------------
// k_wxpose: conv weights -> wt[c][dy][dz][dx]; W0 -> MFMA B fragments (w0f);
// W1 -> MFMA B fragments for fc1 (w1f, 4 K-slices of K=32, cols=16 c). Once.
// ---------------------------------------------------------------------------
__global__ __launch_bounds__(256)
void k_wxpose(const float* __restrict__ cw, float* __restrict__ wt,
              const float* __restrict__ w0, uint4* __restrict__ w0f,
              const float* __restrict__ w1, uint4* __restrict__ w1f) {
    int i = blockIdx.x * 256 + threadIdx.x;
    if (i < 343 * 16) {
        int kidx = i >> 4, c = i & 15;           // kidx = (dz*7+dy)*7+dx
        int dz = kidx / 49, dy = (kidx / 7) % 7, dx = kidx % 7;
        wt[((c*7 + dy)*7 + dz)*7 + dx] = cw[i];
    }
    if (i < 512) {                               // w0f: 8 j-tiles x 64 lanes
        const int jt = i >> 6, l = i & 63;
        const int j = jt*16 + (l & 15), k0 = (l >> 4) * 8;
        u32 v[8];
        #pragma unroll
        for (int q = 0; q < 8; ++q) v[q] = f2bf(w0[(size_t)(k0+q)*H + j]);
        uint4 o = { v[0] | (v[1]<<16), v[2] | (v[3]<<16),
                    v[4] | (v[5]<<16), v[6] | (v[7]<<16) };
        w0f[jt*64 + l] = o;
    }
    if (i < 256) {                               // w1f: 4 K-slices x 64 lanes
        const int kk = i >> 6, l = i & 63;
        const int col = l & 15, k0 = kk*32 + (l >> 4) * 8;
        u32 v[8];
        #pragma unroll
        for (int q = 0; q < 8; ++q) v[q] = f2bf(w1[(size_t)(k0+q)*C + col]);
        uint4 o = { v[0] | (v[1]<<16), v[2] | (v[3]<<16),
                    v[4] | (v[5]<<16), v[6] | (v[7]<<16) };
        w1f[kk*64 + l] = o;
    }
}

// ---------------------------------------------------------------------------
// k_conv v7 (unchanged): bf16 volume, register-cached weights per dy.
// ---------------------------------------------------------------------------
__global__ __launch_bounds__(192)
void k_conv(const u16* __restrict__ xp, const float* __restrict__ wt,
            const float* __restrict__ cbias, u16* __restrict__ y1m) {
    const int bid = blockIdx.x;
    const int zt = bid & 15;          // 16 z-tiles of 3
    const int yt = (bid >> 4) % 3;    // 3 y-tiles of 16
    const int c  = (bid / 48) & 15;
    const int b  = bid / 768;
    const int t  = threadIdx.x;
    const int tx = t % 12, ty = t / 12;
    const int y0 = yt * 16, z0 = zt * 3;
    const u16* base = xp + (size_t)(b*16 + c) * PVOL
                         + (size_t)(y0 + ty) * PROW + 4*tx
                         + (size_t)z0 * PPL;
    const float* wc = wt + c * 343;   // [dy][dz][dx]

    float a[3][4];
    #pragma unroll
    for (int k = 0; k < 3; ++k)
        a[k][0] = a[k][1] = a[k][2] = a[k][3] = 0.f;

    for (int dy = 0; dy < 7; ++dy) {              // runtime: body fits I$
        float w[49];
        const float* wrow = wc + dy*49;
        #pragma unroll
        for (int q = 0; q < 12; ++q) {
            float4 p = *(const float4*)(wrow + q*4);
            w[q*4+0] = p.x; w[q*4+1] = p.y; w[q*4+2] = p.z; w[q*4+3] = p.w;
        }
        w[48] = wrow[48];
        const u16* rowb = base + (size_t)dy * PROW;
        #pragma unroll
        for (int pz = 0; pz < 9; ++pz) {          // input plane zi = z0+pz-3
            const u16* rp = rowb + (size_t)pz * PPL;
            const uint2 p01 = *(const uint2*)rp;
            const uint2 p23 = *(const uint2*)(rp + 4);
            const u32  p4  = *(const u32*)(rp + 8);
            const float v0 = lof(p01.x), v1 = hif(p01.x);
            const float v2 = lof(p01.y), v3 = hif(p01.y);
            const float v4 = lof(p23.x), v5 = hif(p23.x);
            const float v6 = lof(p23.y), v7 = hif(p23.y);
            const float v8 = lof(p4),    v9 = hif(p4);
            #pragma unroll
            for (int k = 0; k < 3; ++k) {
                const int dz = pz - k;            // compile-time
                if (dz >= 0 && dz <= 6) {
                    const float w0=w[dz*7+0], w1=w[dz*7+1], w2=w[dz*7+2],
                                w3=w[dz*7+3], w4=w[dz*7+4], w5=w[dz*7+5],
                                w6=w[dz*7+6];
                    a[k][0] = fmaf(w0,v0, fmaf(w1,v1, fmaf(w2,v2, fmaf(w3,v3,
                              fmaf(w4,v4, fmaf(w5,v5, fmaf(w6,v6, a[k][0])))))));
                    a[k][1] = fmaf(w0,v1, fmaf(w1,v2, fmaf(w2,v3, fmaf(w3,v4,
                              fmaf(w4,v5, fmaf(w5,v6, fmaf(w6,v7, a[k][1])))))));
                    a[k][2] = fmaf(w0,v2, fmaf(w1,v3, fmaf(w2,v4, fmaf(w3,v5,
                              fmaf(w4,v6, fmaf(w5,v7, fmaf(w6,v8, a[k][2])))))));
                    a[k][3] = fmaf(w0,v3, fmaf(w1,v4, fmaf(w2,v5, fmaf(w3,v6,
                              fmaf(w4,v7, fmaf(w5,v8, fmaf(w6,v9, a[k][3])))))));
                }
            }
        }
    }

    const float cbv = cbias[c];
    const size_t cb_off = (size_t)(b*16 + c) * D3;
    #pragma unroll
    for (int k = 0; k < 3; ++k) {
        const size_t sp = (size_t)(z0+k)*2304 + (y0+ty)*48 + 4*tx;
        ushort4 o = { f2bf(a[k][0]+cbv), f2bf(a[k][1]+cbv),
                      f2bf(a[k][2]+cbv), f2bf(a[k][3]+cbv) };
        *(ushort4*)(y1m + cb_off + sp) = o;
    }
}

// ---------------------------------------------------------------------------
// MFMA A-fragment builder shared by fc0/apply: lane=(vx=l&15 feeds voxel,
// ks=l>>4 feeds K-slice); ks 0-1 = x (global f32->bf16), ks 2-3 = y1 (LDS).
// ---------------------------------------------------------------------------
__device__ __forceinline__ bf16x8 fc0_afrag(const float* __restrict__ srcx,
                                            const u16 (*ys)[128],
                                            int vb0, int vfeed, int ks) {
    bf16x8 A;
    if (ks < 2) {
        const float4* xp4 = (const float4*)(srcx + (size_t)(vb0+vfeed)*C + ks*8);
        float4 p0 = xp4[0], p1 = xp4[1];
        A[0]=(short)f2bf(p0.x); A[1]=(short)f2bf(p0.y);
        A[2]=(short)f2bf(p0.z); A[3]=(short)f2bf(p0.w);
        A[4]=(short)f2bf(p1.x); A[5]=(short)f2bf(p1.y);
        A[6]=(short)f2bf(p1.z); A[7]=(short)f2bf(p1.w);
    } else {
        const int c0 = (ks - 2) * 8;
        #pragma unroll
        for (int i = 0; i < 8; ++i) A[i] = (short)ys[c0+i][vfeed];
    }
    return A;
}

// ---------------------------------------------------------------------------
// k_fc0 v15: BN-stats-only pass (hb store deleted — h is recomputed in
// k_apply). MFMA h, accumulate sum/sq per lane, padded-LDS reduce.
// ---------------------------------------------------------------------------
__global__ __launch_bounds__(256)
void k_fc0(const float* __restrict__ srcx, const u16* __restrict__ y1m,
           const uint4* __restrict__ w0f, const float* __restrict__ b0,
           float* __restrict__ partials) {
    __shared__ u16 ys[16][128];         // 4 KB
    __shared__ float red[2][128][17];   // 17.4 KB
    const int t = threadIdx.x;
    const int lane = t & 63, wv = t >> 6;
    const int vb0 = blockIdx.x * 128;
    const int b  = vb0 / D3;
    const int sp0 = vb0 - b * D3;
    {
        const u16* yb = y1m + (size_t)b*16*D3 + sp0;
        #pragma unroll
        for (int r = 0; r < 2; ++r) {
            const int idx = t + 256*r;
            const int cc = idx >> 5, q = idx & 31;
            *(ushort4*)&ys[cc][q*4] = *(const ushort4*)(yb + (size_t)cc*D3 + q*4);
        }
    }
    uint4 Bf[8];
    #pragma unroll
    for (int jt = 0; jt < 8; ++jt) Bf[jt] = w0f[jt*64 + lane];
    float bias[8];
    #pragma unroll
    for (int jt = 0; jt < 8; ++jt) bias[jt] = b0[jt*16 + (lane & 15)];
    __syncthreads();

    float sumr[8], sqr[8];
    #pragma unroll
    for (int jt = 0; jt < 8; ++jt) { sumr[jt] = 0.f; sqr[jt] = 0.f; }

    const int vx = lane & 15, ks = lane >> 4;
    #pragma unroll
    for (int tile = 0; tile < 2; ++tile) {
        const int vfeed = wv*32 + tile*16 + vx;
        bf16x8 A = fc0_afrag(srcx, ys, vb0, vfeed, ks);
        #pragma unroll
        for (int jt = 0; jt < 8; ++jt) {
            f32x4 acc = { bias[jt], bias[jt], bias[jt], bias[jt] };
            acc = __builtin_amdgcn_mfma_f32_16x16x32_bf16(
                      A, *(bf16x8*)&Bf[jt], acc, 0, 0, 0);
            #pragma unroll
            for (int r = 0; r < 4; ++r) {
                const float h = acc[r];
                sumr[jt] += h; sqr[jt] = fmaf(h, h, sqr[jt]);
            }
        }
    }
    #pragma unroll
    for (int jt = 0; jt < 8; ++jt) {
        red[0][jt*16 + vx][wv*4 + ks] = sumr[jt];
        red[1][jt*16 + vx][wv*4 + ks] = sqr[jt];
    }
    __syncthreads();
    const int stat = t >> 7, j = t & 127;
    float acc = 0.f;
    #pragma unroll
    for (int g = 0; g < 16; ++g) acc += red[stat][j][g];
    partials[(size_t)t * NB_FC + blockIdx.x] = acc;
}

// ---------------------------------------------------------------------------
__global__ __launch_bounds__(256)
void k_red(const float* __restrict__ partials, float* __restrict__ sums) {
    const int s = blockIdx.x, t = threadIdx.x;
    const float* row = partials + (size_t)s * NB_FC;
    float a = 0.f;
    for (int i = t; i < NB_FC; i += 256) a += row[i];
    __shared__ float l[256];
    l[t] = a; __syncthreads();
    if (t < 128) l[t] += l[t + 128];
    __syncthreads();
    if (t < 64) {
        float v = l[t] + l[t + 64];
        #pragma unroll
        for (int off = 32; off; off >>= 1) v += __shfl_down(v, off);
        if (t == 0) sums[s] = v;
    }
}

// ---------------------------------------------------------------------------
// k_apply v16: recompute h via MFMA, BN-affine+ReLU in-register, h' -> LDS
// [128][132] bf16 (264B rows -> 8B-aligned; read back as 2x uint2 assembled
// through a union — vector elems are not addressable), fc1 = 4x mfma vs
// pre-packed W1, masked residual, ch-0 freeze. xo + xp interior out.
// ---------------------------------------------------------------------------
__global__ __launch_bounds__(256)
void k_apply(const float* __restrict__ srcx, const u16* __restrict__ y1m,
             const uint4* __restrict__ w0f, const float* __restrict__ b0,
             const uint4* __restrict__ w1f,
             const float* __restrict__ gamma, const float* __restrict__ beta,
             const float* __restrict__ sums, const int* __restrict__ mask,
             float* __restrict__ xo, u16* __restrict__ xp) {
    __shared__ u16 ys[16][128];        //  4 KB
    __shared__ u16 hp[128][132];       // 33.8 KB (pitch 132: 264B rows)
    __shared__ float xs[16][132];      //  8.4 KB
    const int t = threadIdx.x;
    const int lane = t & 63, wv = t >> 6;
    const int vb0 = blockIdx.x * 128;
    const int b  = vb0 / D3;
    const int sp0 = vb0 - b * D3;
    {
        const u16* yb = y1m + (size_t)b*16*D3 + sp0;
        #pragma unroll
        for (int r = 0; r < 2; ++r) {
            const int idx = t + 256*r;
            const int cc = idx >> 5, q = idx & 31;
            *(ushort4*)&ys[cc][q*4] = *(const ushort4*)(yb + (size_t)cc*D3 + q*4);
        }
    }
    const int vx = lane & 15, ks = lane >> 4;
    uint4 Bf[8];
    #pragma unroll
    for (int jt = 0; jt < 8; ++jt) Bf[jt] = w0f[jt*64 + lane];
    float bias[8];
    #pragma unroll
    for (int jt = 0; jt < 8; ++jt) bias[jt] = b0[jt*16 + vx];
    uint4 W1f[4];
    #pragma unroll
    for (int kk = 0; kk < 4; ++kk) W1f[kk] = w1f[kk*64 + lane];
    // per-lane BN coefficients for its 8 columns jj = jt*16+vx
    float scv[8], shv[8];
    {
        const float invN = 1.0f / (float)NVOX;
        #pragma unroll
        for (int jt = 0; jt < 8; ++jt) {
            const int jj = jt*16 + vx;
            const float mean = sums[jj] * invN;
            const float var  = fmaf(-mean, mean, sums[H + jj] * invN);
            const float rr = rsqrtf(var + BN_EPS);
            scv[jt] = gamma[jj] * rr;
            shv[jt] = beta[jj] - mean * scv[jt];
        }
    }
    __syncthreads();

    // phase A: recompute h, BN+ReLU, write h' (bf16) to LDS
    #pragma unroll
    for (int tile = 0; tile < 2; ++tile) {
        const int vfeed = wv*32 + tile*16 + vx;
        bf16x8 A = fc0_afrag(srcx, ys, vb0, vfeed, ks);
        const int vrow0 = wv*32 + tile*16 + (ks << 2);
        #pragma unroll
        for (int jt = 0; jt < 8; ++jt) {
            f32x4 acc = { bias[jt], bias[jt], bias[jt], bias[jt] };
            acc = __builtin_amdgcn_mfma_f32_16x16x32_bf16(
                      A, *(bf16x8*)&Bf[jt], acc, 0, 0, 0);
            const int jj = jt*16 + vx;
            #pragma unroll
            for (int r = 0; r < 4; ++r) {
                const float hq = fmaxf(0.f, fmaf(acc[r], scv[jt], shv[jt]));
                hp[vrow0 + r][jj] = f2bf(hq);
            }
        }
    }
    // phase B: fc1 via MFMA — each wave consumes only rows it wrote (no
    // __syncthreads; compiler orders same-array LDS ops via lgkmcnt).
    #pragma unroll
    for (int tile = 0; tile < 2; ++tile) {
        const int vfeed = wv*32 + tile*16 + vx;
        f32x4 acc1 = { 0.f, 0.f, 0.f, 0.f };
        #pragma unroll
        for (int kk = 0; kk < 4; ++kk) {
            union { uint4 u; bf16x8 v; } a1;
            const uint2 q0 = *(const uint2*)&hp[vfeed][kk*32 + ks*8];
            const uint2 q1 = *(const uint2*)&hp[vfeed][kk*32 + ks*8 + 4];
            a1.u.x = q0.x; a1.u.y = q0.y; a1.u.z = q1.x; a1.u.w = q1.y;
            acc1 = __builtin_amdgcn_mfma_f32_16x16x32_bf16(
                       a1.v, *(bf16x8*)&W1f[kk], acc1, 0, 0, 0);
        }
        const int vrow0 = wv*32 + tile*16 + (ks << 2);
        #pragma unroll
        for (int r = 0; r < 4; ++r) {
            const int vl = vrow0 + r;
            const size_t v = (size_t)vb0 + vl;
            const float m = (float)mask[v];
            const float xold = srcx[v*C + vx];
            const float xn = (vx == 0) ? xold : fmaf(acc1[r], m, xold);
            xo[v*C + vx] = xn;
            xs[vx][vl] = xn;
        }
    }
    __syncthreads();
    // phase C: bf16 padded-volume interior, coalesced per channel
    #pragma unroll
    for (int r = 0; r < 8; ++r) {
        const int idx = t + 256*r;          // 0..2047
        const int c2 = idx >> 7, vi = idx & 127;
        const int s = sp0 + vi;
        const int z = s / 2304, rem = s - z*2304;
        const int yy = rem / 48, x0 = rem - yy*48;
        xp[(size_t)(b*16 + c2)*PVOL + (size_t)(z+3)*PPL
           + (yy+3)*PROW + (x0+3)] = f2bf(xs[c2][vi]);
    }
}

// ---------------------------------------------------------------------------
extern "C" void kernel_launch(void* const* d_in, const int* in_sizes, int n_in,
                              void* d_out, int out_size, void* d_ws, size_t ws_size,
                              hipStream_t stream) {
    const float* x_in = (const float*)d_in[0];
    const float* cw   = (const float*)d_in[1];
    const float* cb   = (const float*)d_in[2];
    const float* w0   = (const float*)d_in[3];
    const float* b0   = (const float*)d_in[4];
    const float* w1   = (const float*)d_in[5];
    const float* gm   = (const float*)d_in[6];
    const float* bt   = (const float*)d_in[7];
    const int*   mk   = (const int*)d_in[8];
    float* out = (float*)d_out;

    char* p = (char*)d_ws;
    u16*   xp       = (u16*)p;     p += (size_t)32 * PVOL * 2;      // 10.4MB
    u16*   y1m      = (u16*)p;     p += (size_t)NVOX * C * 2;       //  7.1MB
    float* partials = (float*)p;   p += (size_t)256 * NB_FC * 4;    //  1.8MB
    float* sums     = (float*)p;   p += 256 * 4;
    float* wt       = (float*)p;   p += 343 * 16 * 4;               // 21.9KB
    uint4* w0f      = (uint4*)p;   p += 512 * 16;                   //  8KB
    uint4* w1f      = (uint4*)p;   p += 256 * 16;                   //  4KB

    k_pad0  <<<32*NPAD/256, 256, 0, stream>>>(x_in, xp);
    k_wxpose<<<22,          256, 0, stream>>>(cw, wt, w0, w0f, w1, w1f);
    for (int s = 0; s < 8; ++s) {
        const float* srcx = (s == 0) ? x_in : out;
        k_conv <<<1536,  192, 0, stream>>>(xp, wt, cb, y1m);
        k_fc0  <<<NB_FC, 256, 0, stream>>>(srcx, y1m, w0f, b0, partials);
        k_red  <<<256,   256, 0, stream>>>(partials, sums);
        k_apply<<<NB_FC, 256, 0, stream>>>(srcx, y1m, w0f, b0, w1f, gm, bt,
                                           sums, mk + (size_t)s * NVOX, out, xp);
        if (s < 7) k_halo<<<32*NPAD/256, 256, 0, stream>>>(xp);
    }
}

// Round 18
// 671.779 us; speedup vs baseline: 1.9168x; 1.0417x over previous
//
#include <hip/hip_runtime.h>

#define D 48
#define C 16
#define H 128
#define D3 (D*D*D)
#define NVOX (2*D3)           // 221184
#define NB_FC (NVOX/128)      // 1728 blocks
#define BN_EPS 1e-5f

// padded channel-major volume (bf16): [b][c][54 z][54 y][56 x]
#define PROW 56
#define PPL  (54*PROW)        // 3024
#define PVOL (54*PPL)         // 163296
#define NPAD (54*54*54)       // 157464

typedef unsigned short u16;
typedef unsigned int   u32;
typedef __attribute__((ext_vector_type(8))) short bf16x8;   // 8 bf16 = 4 VGPR
typedef __attribute__((ext_vector_type(4))) float f32x4;
typedef __attribute__((ext_vector_type(2))) float f32x2;

__device__ __forceinline__ float bf2f(u16 u) {
    union { u32 i; float f; } p; p.i = ((u32)u) << 16; return p.f;
}
__device__ __forceinline__ float lof(u32 u) {
    union { u32 i; float f; } p; p.i = u << 16; return p.f;
}
__device__ __forceinline__ float hif(u32 u) {
    union { u32 i; float f; } p; p.i = u & 0xFFFF0000u; return p.f;
}
__device__ __forceinline__ u16 f2bf(float f) {
    union { float f; u32 i; } p; p.f = f;
    u32 r = p.i + 0x7fffu + ((p.i >> 16) & 1u);   // RTNE
    return (u16)(r >> 16);
}
__device__ __forceinline__ int refl(int i) {
    return i < 0 ? -i : (i >= D ? 2*D - 2 - i : i);
}

// ---------------------------------------------------------------------------
// k_pad0: build full padded bf16 volume from channels-last x_in (once).
// ---------------------------------------------------------------------------
__global__ __launch_bounds__(256)
void k_pad0(const float* __restrict__ x, u16* __restrict__ xp) {
    const int idx = blockIdx.x * 256 + threadIdx.x;     // 32*NPAD exactly
    const int bc = idx / NPAD;
    int r = idx - bc * NPAD;
    const int pz = r / 2916; r -= pz * 2916;
    const int py = r / 54;
    const int px = r - py * 54;
    const int b = bc >> 4, c = bc & 15;
    const int z = refl(pz - 3), y = refl(py - 3), x0 = refl(px - 3);
    xp[(size_t)bc*PVOL + pz*PPL + py*PROW + px] =
        f2bf(x[(((size_t)(b*D + z))*D + y)*D*C + x0*C + c]);
}

// ---------------------------------------------------------------------------
// k_halo: refresh halo shells from interior (interior written by k_apply).
// ---------------------------------------------------------------------------
__global__ __launch_bounds__(256)
void k_halo(u16* __restrict__ xp) {
    const int idx = blockIdx.x * 256 + threadIdx.x;
    const int bc = idx / NPAD;
    int r = idx - bc * NPAD;
    const int pz = r / 2916; r -= pz * 2916;
    const int py = r / 54;
    const int px = r - py * 54;
    if (pz >= 3 && pz < 51 && py >= 3 && py < 51 && px >= 3 && px < 51) return;
    const int sz = refl(pz-3) + 3, sy = refl(py-3) + 3, sx = refl(px-3) + 3;
    xp[(size_t)bc*PVOL + pz*PPL + py*PROW + px] =
        xp[(size_t)bc*PVOL + sz*PPL + sy*PROW + sx];
}

// ---------------------------------------------------------------------------
// k_wxpose: conv weights -> wt[c][dy][dz][dx]; W0 -> MFMA B fragments (w0f);
// W1 -> MFMA B fragments for fc1 (w1f, 4 K-slices of K=32, cols=16 c). Once.
// ---------------------------------------------------------------------------
__global__ __launch_bounds__(256)
void k_wxpose(const float* __restrict__ cw, float* __restrict__ wt,
              const float* __restrict__ w0, uint4* __restrict__ w0f,
              const float* __restrict__ w1, uint4* __restrict__ w1f) {
    int i = blockIdx.x * 256 + threadIdx.x;
    if (i < 343 * 16) {
        int kidx = i >> 4, c = i & 15;           // kidx = (dz*7+dy)*7+dx
        int dz = kidx / 49, dy = (kidx / 7) % 7, dx = kidx % 7;
        wt[((c*7 + dy)*7 + dz)*7 + dx] = cw[i];
    }
    if (i < 512) {                               // w0f: 8 j-tiles x 64 lanes
        const int jt = i >> 6, l = i & 63;
        const int j = jt*16 + (l & 15), k0 = (l >> 4) * 8;
        u32 v[8];
        #pragma unroll
        for (int q = 0; q < 8; ++q) v[q] = f2bf(w0[(size_t)(k0+q)*H + j]);
        uint4 o = { v[0] | (v[1]<<16), v[2] | (v[3]<<16),
                    v[4] | (v[5]<<16), v[6] | (v[7]<<16) };
        w0f[jt*64 + l] = o;
    }
    if (i < 256) {                               // w1f: 4 K-slices x 64 lanes
        const int kk = i >> 6, l = i & 63;
        const int col = l & 15, k0 = kk*32 + (l >> 4) * 8;
        u32 v[8];
        #pragma unroll
        for (int q = 0; q < 8; ++q) v[q] = f2bf(w1[(size_t)(k0+q)*C + col]);
        uint4 o = { v[0] | (v[1]<<16), v[2] | (v[3]<<16),
                    v[4] | (v[5]<<16), v[6] | (v[7]<<16) };
        w1f[kk*64 + l] = o;
    }
}

// ---------------------------------------------------------------------------
// k_conv v8: v7 + packed-f32 FMA. The 4 consecutive x-outputs are computed
// as two f32x2 accumulators (out0,out1)/(out2,out3); per (dy,pz) row build
// 9 shifted pairs (v[i],v[i+1]) and issue 42 v_pk_fma_f32 instead of 84
// scalar v_fma_f32 (__builtin_elementwise_fma on f32x2 lowers to pk on
// gfx90a+; worst case it splits back to 2 FMAs = null, not regression).
// ---------------------------------------------------------------------------
__global__ __launch_bounds__(192)
void k_conv(const u16* __restrict__ xp, const float* __restrict__ wt,
            const float* __restrict__ cbias, u16* __restrict__ y1m) {
    const int bid = blockIdx.x;
    const int zt = bid & 15;          // 16 z-tiles of 3
    const int yt = (bid >> 4) % 3;    // 3 y-tiles of 16
    const int c  = (bid / 48) & 15;
    const int b  = bid / 768;
    const int t  = threadIdx.x;
    const int tx = t % 12, ty = t / 12;
    const int y0 = yt * 16, z0 = zt * 3;
    const u16* base = xp + (size_t)(b*16 + c) * PVOL
                         + (size_t)(y0 + ty) * PROW + 4*tx
                         + (size_t)z0 * PPL;
    const float* wc = wt + c * 343;   // [dy][dz][dx]

    f32x2 a01[3], a23[3];
    #pragma unroll
    for (int k = 0; k < 3; ++k) {
        a01[k] = (f32x2){0.f, 0.f};
        a23[k] = (f32x2){0.f, 0.f};
    }

    for (int dy = 0; dy < 7; ++dy) {              // runtime: body fits I$
        float w[49];
        const float* wrow = wc + dy*49;
        #pragma unroll
        for (int q = 0; q < 12; ++q) {
            float4 p = *(const float4*)(wrow + q*4);
            w[q*4+0] = p.x; w[q*4+1] = p.y; w[q*4+2] = p.z; w[q*4+3] = p.w;
        }
        w[48] = wrow[48];
        const u16* rowb = base + (size_t)dy * PROW;
        #pragma unroll
        for (int pz = 0; pz < 9; ++pz) {          // input plane zi = z0+pz-3
            const u16* rp = rowb + (size_t)pz * PPL;
            const uint2 p01 = *(const uint2*)rp;
            const uint2 p23 = *(const uint2*)(rp + 4);
            const u32  p4  = *(const u32*)(rp + 8);
            float v[10];
            v[0] = lof(p01.x); v[1] = hif(p01.x);
            v[2] = lof(p01.y); v[3] = hif(p01.y);
            v[4] = lof(p23.x); v[5] = hif(p23.x);
            v[6] = lof(p23.y); v[7] = hif(p23.y);
            v[8] = lof(p4);    v[9] = hif(p4);
            f32x2 pr[9];
            #pragma unroll
            for (int i = 0; i < 9; ++i) pr[i] = (f32x2){v[i], v[i+1]};
            #pragma unroll
            for (int k = 0; k < 3; ++k) {
                const int dz = pz - k;            // compile-time
                if (dz >= 0 && dz <= 6) {
                    const float* wz = w + dz*7;
                    #pragma unroll
                    for (int dx = 0; dx < 7; ++dx) {
                        const f32x2 w2 = (f32x2){wz[dx], wz[dx]};
                        a01[k] = __builtin_elementwise_fma(w2, pr[dx], a01[k]);
                        a23[k] = __builtin_elementwise_fma(w2, pr[dx+2], a23[k]);
                    }
                }
            }
        }
    }

    const float cbv = cbias[c];
    const size_t cb_off = (size_t)(b*16 + c) * D3;
    #pragma unroll
    for (int k = 0; k < 3; ++k) {
        const size_t sp = (size_t)(z0+k)*2304 + (y0+ty)*48 + 4*tx;
        ushort4 o = { f2bf(a01[k].x+cbv), f2bf(a01[k].y+cbv),
                      f2bf(a23[k].x+cbv), f2bf(a23[k].y+cbv) };
        *(ushort4*)(y1m + cb_off + sp) = o;
    }
}

// ---------------------------------------------------------------------------
// MFMA A-fragment builder shared by fc0/apply: lane=(vx=l&15 feeds voxel,
// ks=l>>4 feeds K-slice); ks 0-1 = x (global f32->bf16), ks 2-3 = y1 (LDS).
// ---------------------------------------------------------------------------
__device__ __forceinline__ bf16x8 fc0_afrag(const float* __restrict__ srcx,
                                            const u16 (*ys)[128],
                                            int vb0, int vfeed, int ks) {
    bf16x8 A;
    if (ks < 2) {
        const float4* xp4 = (const float4*)(srcx + (size_t)(vb0+vfeed)*C + ks*8);
        float4 p0 = xp4[0], p1 = xp4[1];
        A[0]=(short)f2bf(p0.x); A[1]=(short)f2bf(p0.y);
        A[2]=(short)f2bf(p0.z); A[3]=(short)f2bf(p0.w);
        A[4]=(short)f2bf(p1.x); A[5]=(short)f2bf(p1.y);
        A[6]=(short)f2bf(p1.z); A[7]=(short)f2bf(p1.w);
    } else {
        const int c0 = (ks - 2) * 8;
        #pragma unroll
        for (int i = 0; i < 8; ++i) A[i] = (short)ys[c0+i][vfeed];
    }
    return A;
}

// ---------------------------------------------------------------------------
// k_fc0 v15 (unchanged): BN-stats-only MFMA pass.
// ---------------------------------------------------------------------------
__global__ __launch_bounds__(256)
void k_fc0(const float* __restrict__ srcx, const u16* __restrict__ y1m,
           const uint4* __restrict__ w0f, const float* __restrict__ b0,
           float* __restrict__ partials) {
    __shared__ u16 ys[16][128];         // 4 KB
    __shared__ float red[2][128][17];   // 17.4 KB
    const int t = threadIdx.x;
    const int lane = t & 63, wv = t >> 6;
    const int vb0 = blockIdx.x * 128;
    const int b  = vb0 / D3;
    const int sp0 = vb0 - b * D3;
    {
        const u16* yb = y1m + (size_t)b*16*D3 + sp0;
        #pragma unroll
        for (int r = 0; r < 2; ++r) {
            const int idx = t + 256*r;
            const int cc = idx >> 5, q = idx & 31;
            *(ushort4*)&ys[cc][q*4] = *(const ushort4*)(yb + (size_t)cc*D3 + q*4);
        }
    }
    uint4 Bf[8];
    #pragma unroll
    for (int jt = 0; jt < 8; ++jt) Bf[jt] = w0f[jt*64 + lane];
    float bias[8];
    #pragma unroll
    for (int jt = 0; jt < 8; ++jt) bias[jt] = b0[jt*16 + (lane & 15)];
    __syncthreads();

    float sumr[8], sqr[8];
    #pragma unroll
    for (int jt = 0; jt < 8; ++jt) { sumr[jt] = 0.f; sqr[jt] = 0.f; }

    const int vx = lane & 15, ks = lane >> 4;
    #pragma unroll
    for (int tile = 0; tile < 2; ++tile) {
        const int vfeed = wv*32 + tile*16 + vx;
        bf16x8 A = fc0_afrag(srcx, ys, vb0, vfeed, ks);
        #pragma unroll
        for (int jt = 0; jt < 8; ++jt) {
            f32x4 acc = { bias[jt], bias[jt], bias[jt], bias[jt] };
            acc = __builtin_amdgcn_mfma_f32_16x16x32_bf16(
                      A, *(bf16x8*)&Bf[jt], acc, 0, 0, 0);
            #pragma unroll
            for (int r = 0; r < 4; ++r) {
                const float h = acc[r];
                sumr[jt] += h; sqr[jt] = fmaf(h, h, sqr[jt]);
            }
        }
    }
    #pragma unroll
    for (int jt = 0; jt < 8; ++jt) {
        red[0][jt*16 + vx][wv*4 + ks] = sumr[jt];
        red[1][jt*16 + vx][wv*4 + ks] = sqr[jt];
    }
    __syncthreads();
    const int stat = t >> 7, j = t & 127;
    float acc = 0.f;
    #pragma unroll
    for (int g = 0; g < 16; ++g) acc += red[stat][j][g];
    partials[(size_t)t * NB_FC + blockIdx.x] = acc;
}

// ---------------------------------------------------------------------------
__global__ __launch_bounds__(256)
void k_red(const float* __restrict__ partials, float* __restrict__ sums) {
    const int s = blockIdx.x, t = threadIdx.x;
    const float* row = partials + (size_t)s * NB_FC;
    float a = 0.f;
    for (int i = t; i < NB_FC; i += 256) a += row[i];
    __shared__ float l[256];
    l[t] = a; __syncthreads();
    if (t < 128) l[t] += l[t + 128];
    __syncthreads();
    if (t < 64) {
        float v = l[t] + l[t + 64];
        #pragma unroll
        for (int off = 32; off; off >>= 1) v += __shfl_down(v, off);
        if (t == 0) sums[s] = v;
    }
}

// ---------------------------------------------------------------------------
// k_apply v16 (unchanged): MFMA recompute + BN + fc1-MFMA + residual.
// ---------------------------------------------------------------------------
__global__ __launch_bounds__(256)
void k_apply(const float* __restrict__ srcx, const u16* __restrict__ y1m,
             const uint4* __restrict__ w0f, const float* __restrict__ b0,
             const uint4* __restrict__ w1f,
             const float* __restrict__ gamma, const float* __restrict__ beta,
             const float* __restrict__ sums, const int* __restrict__ mask,
             float* __restrict__ xo, u16* __restrict__ xp) {
    __shared__ u16 ys[16][128];        //  4 KB
    __shared__ u16 hp[128][132];       // 33.8 KB (pitch 132: 264B rows)
    __shared__ float xs[16][132];      //  8.4 KB
    const int t = threadIdx.x;
    const int lane = t & 63, wv = t >> 6;
    const int vb0 = blockIdx.x * 128;
    const int b  = vb0 / D3;
    const int sp0 = vb0 - b * D3;
    {
        const u16* yb = y1m + (size_t)b*16*D3 + sp0;
        #pragma unroll
        for (int r = 0; r < 2; ++r) {
            const int idx = t + 256*r;
            const int cc = idx >> 5, q = idx & 31;
            *(ushort4*)&ys[cc][q*4] = *(const ushort4*)(yb + (size_t)cc*D3 + q*4);
        }
    }
    const int vx = lane & 15, ks = lane >> 4;
    uint4 Bf[8];
    #pragma unroll
    for (int jt = 0; jt < 8; ++jt) Bf[jt] = w0f[jt*64 + lane];
    float bias[8];
    #pragma unroll
    for (int jt = 0; jt < 8; ++jt) bias[jt] = b0[jt*16 + vx];
    uint4 W1f[4];
    #pragma unroll
    for (int kk = 0; kk < 4; ++kk) W1f[kk] = w1f[kk*64 + lane];
    // per-lane BN coefficients for its 8 columns jj = jt*16+vx
    float scv[8], shv[8];
    {
        const float invN = 1.0f / (float)NVOX;
        #pragma unroll
        for (int jt = 0; jt < 8; ++jt) {
            const int jj = jt*16 + vx;
            const float mean = sums[jj] * invN;
            const float var  = fmaf(-mean, mean, sums[H + jj] * invN);
            const float rr = rsqrtf(var + BN_EPS);
            scv[jt] = gamma[jj] * rr;
            shv[jt] = beta[jj] - mean * scv[jt];
        }
    }
    __syncthreads();

    // phase A: recompute h, BN+ReLU, write h' (bf16) to LDS
    #pragma unroll
    for (int tile = 0; tile < 2; ++tile) {
        const int vfeed = wv*32 + tile*16 + vx;
        bf16x8 A = fc0_afrag(srcx, ys, vb0, vfeed, ks);
        const int vrow0 = wv*32 + tile*16 + (ks << 2);
        #pragma unroll
        for (int jt = 0; jt < 8; ++jt) {
            f32x4 acc = { bias[jt], bias[jt], bias[jt], bias[jt] };
            acc = __builtin_amdgcn_mfma_f32_16x16x32_bf16(
                      A, *(bf16x8*)&Bf[jt], acc, 0, 0, 0);
            const int jj = jt*16 + vx;
            #pragma unroll
            for (int r = 0; r < 4; ++r) {
                const float hq = fmaxf(0.f, fmaf(acc[r], scv[jt], shv[jt]));
                hp[vrow0 + r][jj] = f2bf(hq);
            }
        }
    }
    // phase B: fc1 via MFMA — each wave consumes only rows it wrote (no
    // __syncthreads; compiler orders same-array LDS ops via lgkmcnt).
    #pragma unroll
    for (int tile = 0; tile < 2; ++tile) {
        const int vfeed = wv*32 + tile*16 + vx;
        f32x4 acc1 = { 0.f, 0.f, 0.f, 0.f };
        #pragma unroll
        for (int kk = 0; kk < 4; ++kk) {
            union { uint4 u; bf16x8 v; } a1;
            const uint2 q0 = *(const uint2*)&hp[vfeed][kk*32 + ks*8];
            const uint2 q1 = *(const uint2*)&hp[vfeed][kk*32 + ks*8 + 4];
            a1.u.x = q0.x; a1.u.y = q0.y; a1.u.z = q1.x; a1.u.w = q1.y;
            acc1 = __builtin_amdgcn_mfma_f32_16x16x32_bf16(
                       a1.v, *(bf16x8*)&W1f[kk], acc1, 0, 0, 0);
        }
        const int vrow0 = wv*32 + tile*16 + (ks << 2);
        #pragma unroll
        for (int r = 0; r < 4; ++r) {
            const int vl = vrow0 + r;
            const size_t v = (size_t)vb0 + vl;
            const float m = (float)mask[v];
            const float xold = srcx[v*C + vx];
            const float xn = (vx == 0) ? xold : fmaf(acc1[r], m, xold);
            xo[v*C + vx] = xn;
            xs[vx][vl] = xn;
        }
    }
    __syncthreads();
    // phase C: bf16 padded-volume interior, coalesced per channel
    #pragma unroll
    for (int r = 0; r < 8; ++r) {
        const int idx = t + 256*r;          // 0..2047
        const int c2 = idx >> 7, vi = idx & 127;
        const int s = sp0 + vi;
        const int z = s / 2304, rem = s - z*2304;
        const int yy = rem / 48, x0 = rem - yy*48;
        xp[(size_t)(b*16 + c2)*PVOL + (size_t)(z+3)*PPL
           + (yy+3)*PROW + (x0+3)] = f2bf(xs[c2][vi]);
    }
}

// ---------------------------------------------------------------------------
extern "C" void kernel_launch(void* const* d_in, const int* in_sizes, int n_in,
                              void* d_out, int out_size, void* d_ws, size_t ws_size,
                              hipStream_t stream) {
    const float* x_in = (const float*)d_in[0];
    const float* cw   = (const float*)d_in[1];
    const float* cb   = (const float*)d_in[2];
    const float* w0   = (const float*)d_in[3];
    const float* b0   = (const float*)d_in[4];
    const float* w1   = (const float*)d_in[5];
    const float* gm   = (const float*)d_in[6];
    const float* bt   = (const float*)d_in[7];
    const int*   mk   = (const int*)d_in[8];
    float* out = (float*)d_out;

    char* p = (char*)d_ws;
    u16*   xp       = (u16*)p;     p += (size_t)32 * PVOL * 2;      // 10.4MB
    u16*   y1m      = (u16*)p;     p += (size_t)NVOX * C * 2;       //  7.1MB
    float* partials = (float*)p;   p += (size_t)256 * NB_FC * 4;    //  1.8MB
    float* sums     = (float*)p;   p += 256 * 4;
    float* wt       = (float*)p;   p += 343 * 16 * 4;               // 21.9KB
    uint4* w0f      = (uint4*)p;   p += 512 * 16;                   //  8KB
    uint4* w1f      = (uint4*)p;   p += 256 * 16;                   //  4KB

    k_pad0  <<<32*NPAD/256, 256, 0, stream>>>(x_in, xp);
    k_wxpose<<<22,          256, 0, stream>>>(cw, wt, w0, w0f, w1, w1f);
    for (int s = 0; s < 8; ++s) {
        const float* srcx = (s == 0) ? x_in : out;
        k_conv <<<1536,  192, 0, stream>>>(xp, wt, cb, y1m);
        k_fc0  <<<NB_FC, 256, 0, stream>>>(srcx, y1m, w0f, b0, partials);
        k_red  <<<256,   256, 0, stream>>>(partials, sums);
        k_apply<<<NB_FC, 256, 0, stream>>>(srcx, y1m, w0f, b0, w1f, gm, bt,
                                           sums, mk + (size_t)s * NVOX, out, xp);
        if (s < 7) k_halo<<<32*NPAD/256, 256, 0, stream>>>(xp);
    }
}

// Round 19
// 666.478 us; speedup vs baseline: 1.9320x; 1.0080x over previous
//
#include <hip/hip_runtime.h>

#define D 48
#define C 16
#define H 128
#define D3 (D*D*D)
#define NVOX (2*D3)           // 221184
#define NB_FC (NVOX/128)      // 1728 blocks
#define BN_EPS 1e-5f

// padded channel-major volume (bf16): [b][c][54 z][54 y][56 x]
#define PROW 56
#define PPL  (54*PROW)        // 3024
#define PVOL (54*PPL)         // 163296
#define NPAD (54*54*54)       // 157464

typedef unsigned short u16;
typedef unsigned int   u32;
typedef __attribute__((ext_vector_type(8))) short bf16x8;   // 8 bf16 = 4 VGPR
typedef __attribute__((ext_vector_type(4))) float f32x4;
typedef __attribute__((ext_vector_type(2))) float f32x2;

__device__ __forceinline__ float bf2f(u16 u) {
    union { u32 i; float f; } p; p.i = ((u32)u) << 16; return p.f;
}
__device__ __forceinline__ float lof(u32 u) {
    union { u32 i; float f; } p; p.i = u << 16; return p.f;
}
__device__ __forceinline__ float hif(u32 u) {
    union { u32 i; float f; } p; p.i = u & 0xFFFF0000u; return p.f;
}
__device__ __forceinline__ u16 f2bf(float f) {
    union { float f; u32 i; } p; p.f = f;
    u32 r = p.i + 0x7fffu + ((p.i >> 16) & 1u);   // RTNE
    return (u16)(r >> 16);
}
__device__ __forceinline__ int refl(int i) {
    return i < 0 ? -i : (i >= D ? 2*D - 2 - i : i);
}

// ---------------------------------------------------------------------------
// k_pad0: build full padded bf16 volume from channels-last x_in (once).
// ---------------------------------------------------------------------------
__global__ __launch_bounds__(256)
void k_pad0(const float* __restrict__ x, u16* __restrict__ xp) {
    const int idx = blockIdx.x * 256 + threadIdx.x;     // 32*NPAD exactly
    const int bc = idx / NPAD;
    int r = idx - bc * NPAD;
    const int pz = r / 2916; r -= pz * 2916;
    const int py = r / 54;
    const int px = r - py * 54;
    const int b = bc >> 4, c = bc & 15;
    const int z = refl(pz - 3), y = refl(py - 3), x0 = refl(px - 3);
    xp[(size_t)bc*PVOL + pz*PPL + py*PROW + px] =
        f2bf(x[(((size_t)(b*D + z))*D + y)*D*C + x0*C + c]);
}

// ---------------------------------------------------------------------------
// k_halo: refresh halo shells from interior (interior written by k_apply).
// ---------------------------------------------------------------------------
__global__ __launch_bounds__(256)
void k_halo(u16* __restrict__ xp) {
    const int idx = blockIdx.x * 256 + threadIdx.x;
    const int bc = idx / NPAD;
    int r = idx - bc * NPAD;
    const int pz = r / 2916; r -= pz * 2916;
    const int py = r / 54;
    const int px = r - py * 54;
    if (pz >= 3 && pz < 51 && py >= 3 && py < 51 && px >= 3 && px < 51) return;
    const int sz = refl(pz-3) + 3, sy = refl(py-3) + 3, sx = refl(px-3) + 3;
    xp[(size_t)bc*PVOL + pz*PPL + py*PROW + px] =
        xp[(size_t)bc*PVOL + sz*PPL + sy*PROW + sx];
}

// ---------------------------------------------------------------------------
// k_wxpose: conv weights -> wt[c][dy][dz][dx]; W0 -> MFMA B fragments (w0f);
// W1 -> MFMA B fragments for fc1 (w1f, 4 K-slices of K=32, cols=16 c). Once.
// ---------------------------------------------------------------------------
__global__ __launch_bounds__(256)
void k_wxpose(const float* __restrict__ cw, float* __restrict__ wt,
              const float* __restrict__ w0, uint4* __restrict__ w0f,
              const float* __restrict__ w1, uint4* __restrict__ w1f) {
    int i = blockIdx.x * 256 + threadIdx.x;
    if (i < 343 * 16) {
        int kidx = i >> 4, c = i & 15;           // kidx = (dz*7+dy)*7+dx
        int dz = kidx / 49, dy = (kidx / 7) % 7, dx = kidx % 7;
        wt[((c*7 + dy)*7 + dz)*7 + dx] = cw[i];
    }
    if (i < 512) {                               // w0f: 8 j-tiles x 64 lanes
        const int jt = i >> 6, l = i & 63;
        const int j = jt*16 + (l & 15), k0 = (l >> 4) * 8;
        u32 v[8];
        #pragma unroll
        for (int q = 0; q < 8; ++q) v[q] = f2bf(w0[(size_t)(k0+q)*H + j]);
        uint4 o = { v[0] | (v[1]<<16), v[2] | (v[3]<<16),
                    v[4] | (v[5]<<16), v[6] | (v[7]<<16) };
        w0f[jt*64 + l] = o;
    }
    if (i < 256) {                               // w1f: 4 K-slices x 64 lanes
        const int kk = i >> 6, l = i & 63;
        const int col = l & 15, k0 = kk*32 + (l >> 4) * 8;
        u32 v[8];
        #pragma unroll
        for (int q = 0; q < 8; ++q) v[q] = f2bf(w1[(size_t)(k0+q)*C + col]);
        uint4 o = { v[0] | (v[1]<<16), v[2] | (v[3]<<16),
                    v[4] | (v[5]<<16), v[6] | (v[7]<<16) };
        w1f[kk*64 + l] = o;
    }
}

// ---------------------------------------------------------------------------
// k_conv v9: v8 + batched load issue. Per dy: phase 1 issues ALL 27 loads
// of the 9-plane row sweep into register arrays (static unroll -> VGPRs);
// phase 2 unpacks and pk-FMAs the 9 rows (~940 cyc of VALU covers one L2
// round-trip for the whole batch). T14 idiom, wave-local, no LDS/barriers.
// ---------------------------------------------------------------------------
__global__ __launch_bounds__(192)
void k_conv(const u16* __restrict__ xp, const float* __restrict__ wt,
            const float* __restrict__ cbias, u16* __restrict__ y1m) {
    const int bid = blockIdx.x;
    const int zt = bid & 15;          // 16 z-tiles of 3
    const int yt = (bid >> 4) % 3;    // 3 y-tiles of 16
    const int c  = (bid / 48) & 15;
    const int b  = bid / 768;
    const int t  = threadIdx.x;
    const int tx = t % 12, ty = t / 12;
    const int y0 = yt * 16, z0 = zt * 3;
    const u16* base = xp + (size_t)(b*16 + c) * PVOL
                         + (size_t)(y0 + ty) * PROW + 4*tx
                         + (size_t)z0 * PPL;
    const float* wc = wt + c * 343;   // [dy][dz][dx]

    f32x2 a01[3], a23[3];
    #pragma unroll
    for (int k = 0; k < 3; ++k) {
        a01[k] = (f32x2){0.f, 0.f};
        a23[k] = (f32x2){0.f, 0.f};
    }

    for (int dy = 0; dy < 7; ++dy) {              // runtime: body fits I$
        float w[49];
        const float* wrow = wc + dy*49;
        #pragma unroll
        for (int q = 0; q < 12; ++q) {
            float4 p = *(const float4*)(wrow + q*4);
            w[q*4+0] = p.x; w[q*4+1] = p.y; w[q*4+2] = p.z; w[q*4+3] = p.w;
        }
        w[48] = wrow[48];
        const u16* rowb = base + (size_t)dy * PROW;

        // phase 1: issue all 27 loads of this dy-sweep (independent)
        uint2 P01[9], P23[9]; u32 P4[9];
        #pragma unroll
        for (int pz = 0; pz < 9; ++pz) {
            const u16* rp = rowb + (size_t)pz * PPL;
            P01[pz] = *(const uint2*)rp;
            P23[pz] = *(const uint2*)(rp + 4);
            P4[pz]  = *(const u32*)(rp + 8);
        }
        // phase 2: consume
        #pragma unroll
        for (int pz = 0; pz < 9; ++pz) {          // input plane zi = z0+pz-3
            float v[10];
            v[0] = lof(P01[pz].x); v[1] = hif(P01[pz].x);
            v[2] = lof(P01[pz].y); v[3] = hif(P01[pz].y);
            v[4] = lof(P23[pz].x); v[5] = hif(P23[pz].x);
            v[6] = lof(P23[pz].y); v[7] = hif(P23[pz].y);
            v[8] = lof(P4[pz]);    v[9] = hif(P4[pz]);
            f32x2 pr[9];
            #pragma unroll
            for (int i = 0; i < 9; ++i) pr[i] = (f32x2){v[i], v[i+1]};
            #pragma unroll
            for (int k = 0; k < 3; ++k) {
                const int dz = pz - k;            // compile-time
                if (dz >= 0 && dz <= 6) {
                    const float* wz = w + dz*7;
                    #pragma unroll
                    for (int dx = 0; dx < 7; ++dx) {
                        const f32x2 w2 = (f32x2){wz[dx], wz[dx]};
                        a01[k] = __builtin_elementwise_fma(w2, pr[dx], a01[k]);
                        a23[k] = __builtin_elementwise_fma(w2, pr[dx+2], a23[k]);
                    }
                }
            }
        }
    }

    const float cbv = cbias[c];
    const size_t cb_off = (size_t)(b*16 + c) * D3;
    #pragma unroll
    for (int k = 0; k < 3; ++k) {
        const size_t sp = (size_t)(z0+k)*2304 + (y0+ty)*48 + 4*tx;
        ushort4 o = { f2bf(a01[k].x+cbv), f2bf(a01[k].y+cbv),
                      f2bf(a23[k].x+cbv), f2bf(a23[k].y+cbv) };
        *(ushort4*)(y1m + cb_off + sp) = o;
    }
}

// ---------------------------------------------------------------------------
// MFMA A-fragment builder shared by fc0/apply: lane=(vx=l&15 feeds voxel,
// ks=l>>4 feeds K-slice); ks 0-1 = x (global f32->bf16), ks 2-3 = y1 (LDS).
// ---------------------------------------------------------------------------
__device__ __forceinline__ bf16x8 fc0_afrag(const float* __restrict__ srcx,
                                            const u16 (*ys)[128],
                                            int vb0, int vfeed, int ks) {
    bf16x8 A;
    if (ks < 2) {
        const float4* xp4 = (const float4*)(srcx + (size_t)(vb0+vfeed)*C + ks*8);
        float4 p0 = xp4[0], p1 = xp4[1];
        A[0]=(short)f2bf(p0.x); A[1]=(short)f2bf(p0.y);
        A[2]=(short)f2bf(p0.z); A[3]=(short)f2bf(p0.w);
        A[4]=(short)f2bf(p1.x); A[5]=(short)f2bf(p1.y);
        A[6]=(short)f2bf(p1.z); A[7]=(short)f2bf(p1.w);
    } else {
        const int c0 = (ks - 2) * 8;
        #pragma unroll
        for (int i = 0; i < 8; ++i) A[i] = (short)ys[c0+i][vfeed];
    }
    return A;
}

// ---------------------------------------------------------------------------
// k_fc0 v15 (unchanged): BN-stats-only MFMA pass.
// ---------------------------------------------------------------------------
__global__ __launch_bounds__(256)
void k_fc0(const float* __restrict__ srcx, const u16* __restrict__ y1m,
           const uint4* __restrict__ w0f, const float* __restrict__ b0,
           float* __restrict__ partials) {
    __shared__ u16 ys[16][128];         // 4 KB
    __shared__ float red[2][128][17];   // 17.4 KB
    const int t = threadIdx.x;
    const int lane = t & 63, wv = t >> 6;
    const int vb0 = blockIdx.x * 128;
    const int b  = vb0 / D3;
    const int sp0 = vb0 - b * D3;
    {
        const u16* yb = y1m + (size_t)b*16*D3 + sp0;
        #pragma unroll
        for (int r = 0; r < 2; ++r) {
            const int idx = t + 256*r;
            const int cc = idx >> 5, q = idx & 31;
            *(ushort4*)&ys[cc][q*4] = *(const ushort4*)(yb + (size_t)cc*D3 + q*4);
        }
    }
    uint4 Bf[8];
    #pragma unroll
    for (int jt = 0; jt < 8; ++jt) Bf[jt] = w0f[jt*64 + lane];
    float bias[8];
    #pragma unroll
    for (int jt = 0; jt < 8; ++jt) bias[jt] = b0[jt*16 + (lane & 15)];
    __syncthreads();

    float sumr[8], sqr[8];
    #pragma unroll
    for (int jt = 0; jt < 8; ++jt) { sumr[jt] = 0.f; sqr[jt] = 0.f; }

    const int vx = lane & 15, ks = lane >> 4;
    #pragma unroll
    for (int tile = 0; tile < 2; ++tile) {
        const int vfeed = wv*32 + tile*16 + vx;
        bf16x8 A = fc0_afrag(srcx, ys, vb0, vfeed, ks);
        #pragma unroll
        for (int jt = 0; jt < 8; ++jt) {
            f32x4 acc = { bias[jt], bias[jt], bias[jt], bias[jt] };
            acc = __builtin_amdgcn_mfma_f32_16x16x32_bf16(
                      A, *(bf16x8*)&Bf[jt], acc, 0, 0, 0);
            #pragma unroll
            for (int r = 0; r < 4; ++r) {
                const float h = acc[r];
                sumr[jt] += h; sqr[jt] = fmaf(h, h, sqr[jt]);
            }
        }
    }
    #pragma unroll
    for (int jt = 0; jt < 8; ++jt) {
        red[0][jt*16 + vx][wv*4 + ks] = sumr[jt];
        red[1][jt*16 + vx][wv*4 + ks] = sqr[jt];
    }
    __syncthreads();
    const int stat = t >> 7, j = t & 127;
    float acc = 0.f;
    #pragma unroll
    for (int g = 0; g < 16; ++g) acc += red[stat][j][g];
    partials[(size_t)t * NB_FC + blockIdx.x] = acc;
}

// ---------------------------------------------------------------------------
__global__ __launch_bounds__(256)
void k_red(const float* __restrict__ partials, float* __restrict__ sums) {
    const int s = blockIdx.x, t = threadIdx.x;
    const float* row = partials + (size_t)s * NB_FC;
    float a = 0.f;
    for (int i = t; i < NB_FC; i += 256) a += row[i];
    __shared__ float l[256];
    l[t] = a; __syncthreads();
    if (t < 128) l[t] += l[t + 128];
    __syncthreads();
    if (t < 64) {
        float v = l[t] + l[t + 64];
        #pragma unroll
        for (int off = 32; off; off >>= 1) v += __shfl_down(v, off);
        if (t == 0) sums[s] = v;
    }
}

// ---------------------------------------------------------------------------
// k_apply v16 (unchanged): MFMA recompute + BN + fc1-MFMA + residual.
// ---------------------------------------------------------------------------
__global__ __launch_bounds__(256)
void k_apply(const float* __restrict__ srcx, const u16* __restrict__ y1m,
             const uint4* __restrict__ w0f, const float* __restrict__ b0,
             const uint4* __restrict__ w1f,
             const float* __restrict__ gamma, const float* __restrict__ beta,
             const float* __restrict__ sums, const int* __restrict__ mask,
             float* __restrict__ xo, u16* __restrict__ xp) {
    __shared__ u16 ys[16][128];        //  4 KB
    __shared__ u16 hp[128][132];       // 33.8 KB (pitch 132: 264B rows)
    __shared__ float xs[16][132];      //  8.4 KB
    const int t = threadIdx.x;
    const int lane = t & 63, wv = t >> 6;
    const int vb0 = blockIdx.x * 128;
    const int b  = vb0 / D3;
    const int sp0 = vb0 - b * D3;
    {
        const u16* yb = y1m + (size_t)b*16*D3 + sp0;
        #pragma unroll
        for (int r = 0; r < 2; ++r) {
            const int idx = t + 256*r;
            const int cc = idx >> 5, q = idx & 31;
            *(ushort4*)&ys[cc][q*4] = *(const ushort4*)(yb + (size_t)cc*D3 + q*4);
        }
    }
    const int vx = lane & 15, ks = lane >> 4;
    uint4 Bf[8];
    #pragma unroll
    for (int jt = 0; jt < 8; ++jt) Bf[jt] = w0f[jt*64 + lane];
    float bias[8];
    #pragma unroll
    for (int jt = 0; jt < 8; ++jt) bias[jt] = b0[jt*16 + vx];
    uint4 W1f[4];
    #pragma unroll
    for (int kk = 0; kk < 4; ++kk) W1f[kk] = w1f[kk*64 + lane];
    // per-lane BN coefficients for its 8 columns jj = jt*16+vx
    float scv[8], shv[8];
    {
        const float invN = 1.0f / (float)NVOX;
        #pragma unroll
        for (int jt = 0; jt < 8; ++jt) {
            const int jj = jt*16 + vx;
            const float mean = sums[jj] * invN;
            const float var  = fmaf(-mean, mean, sums[H + jj] * invN);
            const float rr = rsqrtf(var + BN_EPS);
            scv[jt] = gamma[jj] * rr;
            shv[jt] = beta[jj] - mean * scv[jt];
        }
    }
    __syncthreads();

    // phase A: recompute h, BN+ReLU, write h' (bf16) to LDS
    #pragma unroll
    for (int tile = 0; tile < 2; ++tile) {
        const int vfeed = wv*32 + tile*16 + vx;
        bf16x8 A = fc0_afrag(srcx, ys, vb0, vfeed, ks);
        const int vrow0 = wv*32 + tile*16 + (ks << 2);
        #pragma unroll
        for (int jt = 0; jt < 8; ++jt) {
            f32x4 acc = { bias[jt], bias[jt], bias[jt], bias[jt] };
            acc = __builtin_amdgcn_mfma_f32_16x16x32_bf16(
                      A, *(bf16x8*)&Bf[jt], acc, 0, 0, 0);
            const int jj = jt*16 + vx;
            #pragma unroll
            for (int r = 0; r < 4; ++r) {
                const float hq = fmaxf(0.f, fmaf(acc[r], scv[jt], shv[jt]));
                hp[vrow0 + r][jj] = f2bf(hq);
            }
        }
    }
    // phase B: fc1 via MFMA — each wave consumes only rows it wrote (no
    // __syncthreads; compiler orders same-array LDS ops via lgkmcnt).
    #pragma unroll
    for (int tile = 0; tile < 2; ++tile) {
        const int vfeed = wv*32 + tile*16 + vx;
        f32x4 acc1 = { 0.f, 0.f, 0.f, 0.f };
        #pragma unroll
        for (int kk = 0; kk < 4; ++kk) {
            union { uint4 u; bf16x8 v; } a1;
            const uint2 q0 = *(const uint2*)&hp[vfeed][kk*32 + ks*8];
            const uint2 q1 = *(const uint2*)&hp[vfeed][kk*32 + ks*8 + 4];
            a1.u.x = q0.x; a1.u.y = q0.y; a1.u.z = q1.x; a1.u.w = q1.y;
            acc1 = __builtin_amdgcn_mfma_f32_16x16x32_bf16(
                       a1.v, *(bf16x8*)&W1f[kk], acc1, 0, 0, 0);
        }
        const int vrow0 = wv*32 + tile*16 + (ks << 2);
        #pragma unroll
        for (int r = 0; r < 4; ++r) {
            const int vl = vrow0 + r;
            const size_t v = (size_t)vb0 + vl;
            const float m = (float)mask[v];
            const float xold = srcx[v*C + vx];
            const float xn = (vx == 0) ? xold : fmaf(acc1[r], m, xold);
            xo[v*C + vx] = xn;
            xs[vx][vl] = xn;
        }
    }
    __syncthreads();
    // phase C: bf16 padded-volume interior, coalesced per channel
    #pragma unroll
    for (int r = 0; r < 8; ++r) {
        const int idx = t + 256*r;          // 0..2047
        const int c2 = idx >> 7, vi = idx & 127;
        const int s = sp0 + vi;
        const int z = s / 2304, rem = s - z*2304;
        const int yy = rem / 48, x0 = rem - yy*48;
        xp[(size_t)(b*16 + c2)*PVOL + (size_t)(z+3)*PPL
           + (yy+3)*PROW + (x0+3)] = f2bf(xs[c2][vi]);
    }
}

// ---------------------------------------------------------------------------
extern "C" void kernel_launch(void* const* d_in, const int* in_sizes, int n_in,
                              void* d_out, int out_size, void* d_ws, size_t ws_size,
                              hipStream_t stream) {
    const float* x_in = (const float*)d_in[0];
    const float* cw   = (const float*)d_in[1];
    const float* cb   = (const float*)d_in[2];
    const float* w0   = (const float*)d_in[3];
    const float* b0   = (const float*)d_in[4];
    const float* w1   = (const float*)d_in[5];
    const float* gm   = (const float*)d_in[6];
    const float* bt   = (const float*)d_in[7];
    const int*   mk   = (const int*)d_in[8];
    float* out = (float*)d_out;

    char* p = (char*)d_ws;
    u16*   xp       = (u16*)p;     p += (size_t)32 * PVOL * 2;      // 10.4MB
    u16*   y1m      = (u16*)p;     p += (size_t)NVOX * C * 2;       //  7.1MB
    float* partials = (float*)p;   p += (size_t)256 * NB_FC * 4;    //  1.8MB
    float* sums     = (float*)p;   p += 256 * 4;
    float* wt       = (float*)p;   p += 343 * 16 * 4;               // 21.9KB
    uint4* w0f      = (uint4*)p;   p += 512 * 16;                   //  8KB
    uint4* w1f      = (uint4*)p;   p += 256 * 16;                   //  4KB

    k_pad0  <<<32*NPAD/256, 256, 0, stream>>>(x_in, xp);
    k_wxpose<<<22,          256, 0, stream>>>(cw, wt, w0, w0f, w1, w1f);
    for (int s = 0; s < 8; ++s) {
        const float* srcx = (s == 0) ? x_in : out;
        k_conv <<<1536,  192, 0, stream>>>(xp, wt, cb, y1m);
        k_fc0  <<<NB_FC, 256, 0, stream>>>(srcx, y1m, w0f, b0, partials);
        k_red  <<<256,   256, 0, stream>>>(partials, sums);
        k_apply<<<NB_FC, 256, 0, stream>>>(srcx, y1m, w0f, b0, w1f, gm, bt,
                                           sums, mk + (size_t)s * NVOX, out, xp);
        if (s < 7) k_halo<<<32*NPAD/256, 256, 0, stream>>>(xp);
    }
}

// Round 20
// 632.595 us; speedup vs baseline: 2.0355x; 1.0536x over previous
//
#include <hip/hip_runtime.h>
#include <hip/hip_fp16.h>

#define D 48
#define C 16
#define H 128
#define D3 (D*D*D)
#define NVOX (2*D3)           // 221184
#define NB_FC (NVOX/128)      // 1728 blocks
#define BN_EPS 1e-5f

// padded channel-major volume (f16): [b][c][54 z][54 y][56 x]
#define PROW 56
#define PPL  (54*PROW)        // 3024
#define PVOL (54*PPL)         // 163296
#define NPAD (54*54*54)       // 157464

typedef unsigned short u16;
typedef unsigned int   u32;
typedef __attribute__((ext_vector_type(8))) short bf16x8;   // 8 bf16 = 4 VGPR
typedef __attribute__((ext_vector_type(4))) float f32x4;
typedef __attribute__((ext_vector_type(2))) _Float16 h16x2;

__device__ __forceinline__ float bf2f(u16 u) {
    union { u32 i; float f; } p; p.i = ((u32)u) << 16; return p.f;
}
__device__ __forceinline__ u16 f2bf(float f) {
    union { float f; u32 i; } p; p.f = f;
    u32 r = p.i + 0x7fffu + ((p.i >> 16) & 1u);   // RTNE
    return (u16)(r >> 16);
}
__device__ __forceinline__ u16 f2h(float f) {     // f32 -> f16 RTNE bits
    return __half_as_ushort(__float2half(f));
}
__device__ __forceinline__ h16x2 ash2(u32 u) {
    union { u32 i; h16x2 h; } p; p.i = u; return p.h;
}
__device__ __forceinline__ int refl(int i) {
    return i < 0 ? -i : (i >= D ? 2*D - 2 - i : i);
}

// ---------------------------------------------------------------------------
// k_pad0: build full padded f16 volume from channels-last x_in (once).
// ---------------------------------------------------------------------------
__global__ __launch_bounds__(256)
void k_pad0(const float* __restrict__ x, u16* __restrict__ xp) {
    const int idx = blockIdx.x * 256 + threadIdx.x;     // 32*NPAD exactly
    const int bc = idx / NPAD;
    int r = idx - bc * NPAD;
    const int pz = r / 2916; r -= pz * 2916;
    const int py = r / 54;
    const int px = r - py * 54;
    const int b = bc >> 4, c = bc & 15;
    const int z = refl(pz - 3), y = refl(py - 3), x0 = refl(px - 3);
    xp[(size_t)bc*PVOL + pz*PPL + py*PROW + px] =
        f2h(x[(((size_t)(b*D + z))*D + y)*D*C + x0*C + c]);
}

// ---------------------------------------------------------------------------
// k_halo: refresh halo shells from interior (raw u16 copy — dtype-agnostic).
// ---------------------------------------------------------------------------
__global__ __launch_bounds__(256)
void k_halo(u16* __restrict__ xp) {
    const int idx = blockIdx.x * 256 + threadIdx.x;
    const int bc = idx / NPAD;
    int r = idx - bc * NPAD;
    const int pz = r / 2916; r -= pz * 2916;
    const int py = r / 54;
    const int px = r - py * 54;
    if (pz >= 3 && pz < 51 && py >= 3 && py < 51 && px >= 3 && px < 51) return;
    const int sz = refl(pz-3) + 3, sy = refl(py-3) + 3, sx = refl(px-3) + 3;
    xp[(size_t)bc*PVOL + pz*PPL + py*PROW + px] =
        xp[(size_t)bc*PVOL + sz*PPL + sy*PROW + sx];
}

// ---------------------------------------------------------------------------
// k_wxpose: conv weights -> f16 dot-pairs wt2[c][dy][dz][4] (pairs
// (w0,w1)(w2,w3)(w4,w5)(w6,0)); W0 -> MFMA B frags (w0f); W1 -> w1f. Once.
// ---------------------------------------------------------------------------
__global__ __launch_bounds__(256)
void k_wxpose(const float* __restrict__ cw, u32* __restrict__ wt2,
              const float* __restrict__ w0, uint4* __restrict__ w0f,
              const float* __restrict__ w1, uint4* __restrict__ w1f) {
    int i = blockIdx.x * 256 + threadIdx.x;
    if (i < 784) {                               // 16 c x 7 dy x 7 dz
        const int c = i / 49, r = i % 49;
        const int dy = r / 7, dz = r % 7;
        #pragma unroll
        for (int q = 0; q < 4; ++q) {
            const int dx0 = 2*q, dx1 = 2*q + 1;
            u32 h0 = f2h(cw[((dz*7 + dy)*7 + dx0)*C + c]);
            u32 h1 = (dx1 < 7) ? f2h(cw[((dz*7 + dy)*7 + dx1)*C + c]) : 0u;
            wt2[(size_t)i*4 + q] = h0 | (h1 << 16);
        }
    }
    if (i < 512) {                               // w0f: 8 j-tiles x 64 lanes
        const int jt = i >> 6, l = i & 63;
        const int j = jt*16 + (l & 15), k0 = (l >> 4) * 8;
        u32 v[8];
        #pragma unroll
        for (int q = 0; q < 8; ++q) v[q] = f2bf(w0[(size_t)(k0+q)*H + j]);
        uint4 o = { v[0] | (v[1]<<16), v[2] | (v[3]<<16),
                    v[4] | (v[5]<<16), v[6] | (v[7]<<16) };
        w0f[jt*64 + l] = o;
    }
    if (i < 256) {                               // w1f: 4 K-slices x 64 lanes
        const int kk = i >> 6, l = i & 63;
        const int col = l & 15, k0 = kk*32 + (l >> 4) * 8;
        u32 v[8];
        #pragma unroll
        for (int q = 0; q < 8; ++q) v[q] = f2bf(w1[(size_t)(k0+q)*C + col]);
        uint4 o = { v[0] | (v[1]<<16), v[2] | (v[3]<<16),
                    v[4] | (v[5]<<16), v[6] | (v[7]<<16) };
        w1f[kk*64 + l] = o;
    }
}

// ---------------------------------------------------------------------------
// k_conv v10: f16 volume + v_dot2 on PACKED pairs — zero unpack/repack.
// Per row: 5 loads-worth of packed pairs P0..P4, 5 v_alignbit for odd pairs
// Q0..Q4, then 16 fdot2 per valid dz (4 outputs x 4 weight-pairs). Weight
// pairs are pre-packed f16 (scalar, uniform). ~42 VALU/row vs ~100 in v9.
// ---------------------------------------------------------------------------
__global__ __launch_bounds__(192)
void k_conv(const u16* __restrict__ xp, const u32* __restrict__ wt2,
            const float* __restrict__ cbias, u16* __restrict__ y1m) {
    const int bid = blockIdx.x;
    const int zt = bid & 15;          // 16 z-tiles of 3
    const int yt = (bid >> 4) % 3;    // 3 y-tiles of 16
    const int c  = (bid / 48) & 15;
    const int b  = bid / 768;
    const int t  = threadIdx.x;
    const int tx = t % 12, ty = t / 12;
    const int y0 = yt * 16, z0 = zt * 3;
    const u16* base = xp + (size_t)(b*16 + c) * PVOL
                         + (size_t)(y0 + ty) * PROW + 4*tx
                         + (size_t)z0 * PPL;

    float a[3][4];
    #pragma unroll
    for (int k = 0; k < 3; ++k)
        a[k][0] = a[k][1] = a[k][2] = a[k][3] = 0.f;

    for (int dy = 0; dy < 7; ++dy) {              // runtime: body fits I$
        // scalar f16 weight-pairs for this (c,dy): 7 dz x 4 pairs (uniform)
        u32 W[7][4];
        const u32* wr = wt2 + ((size_t)(c*7 + dy)*7)*4;
        #pragma unroll
        for (int dz = 0; dz < 7; ++dz) {
            W[dz][0] = wr[dz*4+0]; W[dz][1] = wr[dz*4+1];
            W[dz][2] = wr[dz*4+2]; W[dz][3] = wr[dz*4+3];
        }
        const u16* rowb = base + (size_t)dy * PROW;
        #pragma unroll
        for (int pz = 0; pz < 9; ++pz) {          // input plane zi = z0+pz-3
            const u16* rp = rowb + (size_t)pz * PPL;
            const uint2 p01 = *(const uint2*)rp;
            const uint2 p23 = *(const uint2*)(rp + 4);
            const u32  p4  = *(const u32*)(rp + 8);
            u32 P[5] = { p01.x, p01.y, p23.x, p23.y, p4 };
            u32 Q[5];
            #pragma unroll
            for (int i = 0; i < 4; ++i)
                Q[i] = __builtin_amdgcn_alignbit(P[i+1], P[i], 16);
            Q[4] = P[4] >> 16;                    // (v9, 0)
            #pragma unroll
            for (int k = 0; k < 3; ++k) {
                const int dz = pz - k;            // compile-time
                if (dz >= 0 && dz <= 6) {
                    const u32* Wz = W[dz];
                    #pragma unroll
                    for (int q = 0; q < 4; ++q) {
                        const h16x2 wq = ash2(Wz[q]);
                        a[k][0] = __builtin_amdgcn_fdot2(ash2(P[q]),   wq, a[k][0], false);
                        a[k][1] = __builtin_amdgcn_fdot2(ash2(Q[q]),   wq, a[k][1], false);
                        a[k][2] = __builtin_amdgcn_fdot2(ash2(P[q+1]), wq, a[k][2], false);
                        a[k][3] = __builtin_amdgcn_fdot2(ash2(Q[q+1]), wq, a[k][3], false);
                    }
                }
            }
        }
    }

    const float cbv = cbias[c];
    const size_t cb_off = (size_t)(b*16 + c) * D3;
    #pragma unroll
    for (int k = 0; k < 3; ++k) {
        const size_t sp = (size_t)(z0+k)*2304 + (y0+ty)*48 + 4*tx;
        ushort4 o = { f2bf(a[k][0]+cbv), f2bf(a[k][1]+cbv),
                      f2bf(a[k][2]+cbv), f2bf(a[k][3]+cbv) };
        *(ushort4*)(y1m + cb_off + sp) = o;
    }
}

// ---------------------------------------------------------------------------
// MFMA A-fragment builder shared by fc0/apply: lane=(vx=l&15 feeds voxel,
// ks=l>>4 feeds K-slice); ks 0-1 = x (global f32->bf16), ks 2-3 = y1 (LDS).
// ---------------------------------------------------------------------------
__device__ __forceinline__ bf16x8 fc0_afrag(const float* __restrict__ srcx,
                                            const u16 (*ys)[128],
                                            int vb0, int vfeed, int ks) {
    bf16x8 A;
    if (ks < 2) {
        const float4* xp4 = (const float4*)(srcx + (size_t)(vb0+vfeed)*C + ks*8);
        float4 p0 = xp4[0], p1 = xp4[1];
        A[0]=(short)f2bf(p0.x); A[1]=(short)f2bf(p0.y);
        A[2]=(short)f2bf(p0.z); A[3]=(short)f2bf(p0.w);
        A[4]=(short)f2bf(p1.x); A[5]=(short)f2bf(p1.y);
        A[6]=(short)f2bf(p1.z); A[7]=(short)f2bf(p1.w);
    } else {
        const int c0 = (ks - 2) * 8;
        #pragma unroll
        for (int i = 0; i < 8; ++i) A[i] = (short)ys[c0+i][vfeed];
    }
    return A;
}

// ---------------------------------------------------------------------------
// k_fc0 v15 (unchanged): BN-stats-only MFMA pass.
// ---------------------------------------------------------------------------
__global__ __launch_bounds__(256)
void k_fc0(const float* __restrict__ srcx, const u16* __restrict__ y1m,
           const uint4* __restrict__ w0f, const float* __restrict__ b0,
           float* __restrict__ partials) {
    __shared__ u16 ys[16][128];         // 4 KB
    __shared__ float red[2][128][17];   // 17.4 KB
    const int t = threadIdx.x;
    const int lane = t & 63, wv = t >> 6;
    const int vb0 = blockIdx.x * 128;
    const int b  = vb0 / D3;
    const int sp0 = vb0 - b * D3;
    {
        const u16* yb = y1m + (size_t)b*16*D3 + sp0;
        #pragma unroll
        for (int r = 0; r < 2; ++r) {
            const int idx = t + 256*r;
            const int cc = idx >> 5, q = idx & 31;
            *(ushort4*)&ys[cc][q*4] = *(const ushort4*)(yb + (size_t)cc*D3 + q*4);
        }
    }
    uint4 Bf[8];
    #pragma unroll
    for (int jt = 0; jt < 8; ++jt) Bf[jt] = w0f[jt*64 + lane];
    float bias[8];
    #pragma unroll
    for (int jt = 0; jt < 8; ++jt) bias[jt] = b0[jt*16 + (lane & 15)];
    __syncthreads();

    float sumr[8], sqr[8];
    #pragma unroll
    for (int jt = 0; jt < 8; ++jt) { sumr[jt] = 0.f; sqr[jt] = 0.f; }

    const int vx = lane & 15, ks = lane >> 4;
    #pragma unroll
    for (int tile = 0; tile < 2; ++tile) {
        const int vfeed = wv*32 + tile*16 + vx;
        bf16x8 A = fc0_afrag(srcx, ys, vb0, vfeed, ks);
        #pragma unroll
        for (int jt = 0; jt < 8; ++jt) {
            f32x4 acc = { bias[jt], bias[jt], bias[jt], bias[jt] };
            acc = __builtin_amdgcn_mfma_f32_16x16x32_bf16(
                      A, *(bf16x8*)&Bf[jt], acc, 0, 0, 0);
            #pragma unroll
            for (int r = 0; r < 4; ++r) {
                const float h = acc[r];
                sumr[jt] += h; sqr[jt] = fmaf(h, h, sqr[jt]);
            }
        }
    }
    #pragma unroll
    for (int jt = 0; jt < 8; ++jt) {
        red[0][jt*16 + vx][wv*4 + ks] = sumr[jt];
        red[1][jt*16 + vx][wv*4 + ks] = sqr[jt];
    }
    __syncthreads();
    const int stat = t >> 7, j = t & 127;
    float acc = 0.f;
    #pragma unroll
    for (int g = 0; g < 16; ++g) acc += red[stat][j][g];
    partials[(size_t)t * NB_FC + blockIdx.x] = acc;
}

// ---------------------------------------------------------------------------
__global__ __launch_bounds__(256)
void k_red(const float* __restrict__ partials, float* __restrict__ sums) {
    const int s = blockIdx.x, t = threadIdx.x;
    const float* row = partials + (size_t)s * NB_FC;
    float a = 0.f;
    for (int i = t; i < NB_FC; i += 256) a += row[i];
    __shared__ float l[256];
    l[t] = a; __syncthreads();
    if (t < 128) l[t] += l[t + 128];
    __syncthreads();
    if (t < 64) {
        float v = l[t] + l[t + 64];
        #pragma unroll
        for (int off = 32; off; off >>= 1) v += __shfl_down(v, off);
        if (t == 0) sums[s] = v;
    }
}

// ---------------------------------------------------------------------------
// k_apply v16 (phase C now writes f16): MFMA recompute + BN + fc1-MFMA.
// ---------------------------------------------------------------------------
__global__ __launch_bounds__(256)
void k_apply(const float* __restrict__ srcx, const u16* __restrict__ y1m,
             const uint4* __restrict__ w0f, const float* __restrict__ b0,
             const uint4* __restrict__ w1f,
             const float* __restrict__ gamma, const float* __restrict__ beta,
             const float* __restrict__ sums, const int* __restrict__ mask,
             float* __restrict__ xo, u16* __restrict__ xp) {
    __shared__ u16 ys[16][128];        //  4 KB
    __shared__ u16 hp[128][132];       // 33.8 KB (pitch 132: 264B rows)
    __shared__ float xs[16][132];      //  8.4 KB
    const int t = threadIdx.x;
    const int lane = t & 63, wv = t >> 6;
    const int vb0 = blockIdx.x * 128;
    const int b  = vb0 / D3;
    const int sp0 = vb0 - b * D3;
    {
        const u16* yb = y1m + (size_t)b*16*D3 + sp0;
        #pragma unroll
        for (int r = 0; r < 2; ++r) {
            const int idx = t + 256*r;
            const int cc = idx >> 5, q = idx & 31;
            *(ushort4*)&ys[cc][q*4] = *(const ushort4*)(yb + (size_t)cc*D3 + q*4);
        }
    }
    const int vx = lane & 15, ks = lane >> 4;
    uint4 Bf[8];
    #pragma unroll
    for (int jt = 0; jt < 8; ++jt) Bf[jt] = w0f[jt*64 + lane];
    float bias[8];
    #pragma unroll
    for (int jt = 0; jt < 8; ++jt) bias[jt] = b0[jt*16 + vx];
    uint4 W1f[4];
    #pragma unroll
    for (int kk = 0; kk < 4; ++kk) W1f[kk] = w1f[kk*64 + lane];
    // per-lane BN coefficients for its 8 columns jj = jt*16+vx
    float scv[8], shv[8];
    {
        const float invN = 1.0f / (float)NVOX;
        #pragma unroll
        for (int jt = 0; jt < 8; ++jt) {
            const int jj = jt*16 + vx;
            const float mean = sums[jj] * invN;
            const float var  = fmaf(-mean, mean, sums[H + jj] * invN);
            const float rr = rsqrtf(var + BN_EPS);
            scv[jt] = gamma[jj] * rr;
            shv[jt] = beta[jj] - mean * scv[jt];
        }
    }
    __syncthreads();

    // phase A: recompute h, BN+ReLU, write h' (bf16) to LDS
    #pragma unroll
    for (int tile = 0; tile < 2; ++tile) {
        const int vfeed = wv*32 + tile*16 + vx;
        bf16x8 A = fc0_afrag(srcx, ys, vb0, vfeed, ks);
        const int vrow0 = wv*32 + tile*16 + (ks << 2);
        #pragma unroll
        for (int jt = 0; jt < 8; ++jt) {
            f32x4 acc = { bias[jt], bias[jt], bias[jt], bias[jt] };
            acc = __builtin_amdgcn_mfma_f32_16x16x32_bf16(
                      A, *(bf16x8*)&Bf[jt], acc, 0, 0, 0);
            const int jj = jt*16 + vx;
            #pragma unroll
            for (int r = 0; r < 4; ++r) {
                const float hq = fmaxf(0.f, fmaf(acc[r], scv[jt], shv[jt]));
                hp[vrow0 + r][jj] = f2bf(hq);
            }
        }
    }
    // phase B: fc1 via MFMA — each wave consumes only rows it wrote (no
    // __syncthreads; compiler orders same-array LDS ops via lgkmcnt).
    #pragma unroll
    for (int tile = 0; tile < 2; ++tile) {
        const int vfeed = wv*32 + tile*16 + vx;
        f32x4 acc1 = { 0.f, 0.f, 0.f, 0.f };
        #pragma unroll
        for (int kk = 0; kk < 4; ++kk) {
            union { uint4 u; bf16x8 v; } a1;
            const uint2 q0 = *(const uint2*)&hp[vfeed][kk*32 + ks*8];
            const uint2 q1 = *(const uint2*)&hp[vfeed][kk*32 + ks*8 + 4];
            a1.u.x = q0.x; a1.u.y = q0.y; a1.u.z = q1.x; a1.u.w = q1.y;
            acc1 = __builtin_amdgcn_mfma_f32_16x16x32_bf16(
                       a1.v, *(bf16x8*)&W1f[kk], acc1, 0, 0, 0);
        }
        const int vrow0 = wv*32 + tile*16 + (ks << 2);
        #pragma unroll
        for (int r = 0; r < 4; ++r) {
            const int vl = vrow0 + r;
            const size_t v = (size_t)vb0 + vl;
            const float m = (float)mask[v];
            const float xold = srcx[v*C + vx];
            const float xn = (vx == 0) ? xold : fmaf(acc1[r], m, xold);
            xo[v*C + vx] = xn;
            xs[vx][vl] = xn;
        }
    }
    __syncthreads();
    // phase C: f16 padded-volume interior, coalesced per channel
    #pragma unroll
    for (int r = 0; r < 8; ++r) {
        const int idx = t + 256*r;          // 0..2047
        const int c2 = idx >> 7, vi = idx & 127;
        const int s = sp0 + vi;
        const int z = s / 2304, rem = s - z*2304;
        const int yy = rem / 48, x0 = rem - yy*48;
        xp[(size_t)(b*16 + c2)*PVOL + (size_t)(z+3)*PPL
           + (yy+3)*PROW + (x0+3)] = f2h(xs[c2][vi]);
    }
}

// ---------------------------------------------------------------------------
extern "C" void kernel_launch(void* const* d_in, const int* in_sizes, int n_in,
                              void* d_out, int out_size, void* d_ws, size_t ws_size,
                              hipStream_t stream) {
    const float* x_in = (const float*)d_in[0];
    const float* cw   = (const float*)d_in[1];
    const float* cb   = (const float*)d_in[2];
    const float* w0   = (const float*)d_in[3];
    const float* b0   = (const float*)d_in[4];
    const float* w1   = (const float*)d_in[5];
    const float* gm   = (const float*)d_in[6];
    const float* bt   = (const float*)d_in[7];
    const int*   mk   = (const int*)d_in[8];
    float* out = (float*)d_out;

    char* p = (char*)d_ws;
    u16*   xp       = (u16*)p;     p += (size_t)32 * PVOL * 2;      // 10.4MB
    u16*   y1m      = (u16*)p;     p += (size_t)NVOX * C * 2;       //  7.1MB
    float* partials = (float*)p;   p += (size_t)256 * NB_FC * 4;    //  1.8MB
    float* sums     = (float*)p;   p += 256 * 4;
    u32*   wt2      = (u32*)p;     p += 784 * 4 * 4;                // 12.5KB
    uint4* w0f      = (uint4*)p;   p += 512 * 16;                   //  8KB
    uint4* w1f      = (uint4*)p;   p += 256 * 16;                   //  4KB

    k_pad0  <<<32*NPAD/256, 256, 0, stream>>>(x_in, xp);
    k_wxpose<<<22,          256, 0, stream>>>(cw, wt2, w0, w0f, w1, w1f);
    for (int s = 0; s < 8; ++s) {
        const float* srcx = (s == 0) ? x_in : out;
        k_conv <<<1536,  192, 0, stream>>>(xp, wt2, cb, y1m);
        k_fc0  <<<NB_FC, 256, 0, stream>>>(srcx, y1m, w0f, b0, partials);
        k_red  <<<256,   256, 0, stream>>>(partials, sums);
        k_apply<<<NB_FC, 256, 0, stream>>>(srcx, y1m, w0f, b0, w1f, gm, bt,
                                           sums, mk + (size_t)s * NVOX, out, xp);
        if (s < 7) k_halo<<<32*NPAD/256, 256, 0, stream>>>(xp);
    }
}